// Round 2
// baseline (1439.158 us; speedup 1.0000x reference)
//
#include <hip/hip_runtime.h>
#include <cstdint>
#include <cstddef>

#define TEXTD 768
#define VISD  512
#define AUDD  128

__device__ __forceinline__ float wred_sum(float v){
  #pragma unroll
  for (int m = 32; m >= 1; m >>= 1) v += __shfl_xor(v, m, 64);
  return v;
}

// ---------------- type bucketing (counting sort by node_type) ----------------
__global__ void k_tcount(const int* __restrict__ ntype, int nN, int* __restrict__ tcnt){
  int i = blockIdx.x*blockDim.x + threadIdx.x;
  if (i < nN) atomicAdd(&tcnt[ntype[i]], 1);
}
__global__ void k_toffs(const int* __restrict__ tcnt, int* __restrict__ toff, int* __restrict__ tpos){
  toff[0] = 0; toff[1] = tcnt[0]; toff[2] = tcnt[0] + tcnt[1];
  tpos[0] = 0; tpos[1] = tcnt[0]; tpos[2] = tcnt[0] + tcnt[1];
}
__global__ void k_tscatter(const int* __restrict__ ntype, int nN, int* __restrict__ tpos,
                           int* __restrict__ order){
  int i = blockIdx.x*blockDim.x + threadIdx.x;
  if (i < nN){
    int p = atomicAdd(&tpos[ntype[i]], 1);
    order[p] = i;
  }
}

// ---------------- projection as bucketed tiled GEMM ----------------
// grid = (ceil(N/64), 3). Block: 256 thr; 64 nodes x 64 chans; 4x4 register tile/thread.
__global__ __launch_bounds__(256) void k_projgemm(const float* __restrict__ x,
    const int* __restrict__ order, const int* __restrict__ toff, const int* __restrict__ tcnt,
    const float* __restrict__ Wt, const float* __restrict__ bt,
    const float* __restrict__ Wv, const float* __restrict__ bv,
    const float* __restrict__ Wa, const float* __restrict__ ba,
    float* __restrict__ h0){
  int ty = blockIdx.y;
  int cnt = tcnt[ty];
  int tile = blockIdx.x;
  if (tile*64 >= cnt) return;
  const float* W; const float* bias; int dim;
  if (ty == 0)      { W = Wt; bias = bt; dim = TEXTD; }
  else if (ty == 1) { W = Wv; bias = bv; dim = VISD; }
  else              { W = Wa; bias = ba; dim = AUDD; }
  int off = toff[ty];

  __shared__ float xsT[64][68];   // transposed x chunk: [kk][node], pad->b128-aligned, ~2-way banks
  __shared__ float ws [64][68];   // W chunk: [kk][chan]
  __shared__ int   nid[64];

  int t = threadIdx.x;
  if (t < 64){
    int idx = tile*64 + t;
    nid[t] = (idx < cnt) ? order[off + idx] : -1;
  }
  __syncthreads();

  int node_l = t & 63;
  int ndl = nid[node_l];
  const float* xrow = x + (size_t)(ndl < 0 ? 0 : ndl) * TEXTD;
  int wrow = t >> 2, wu = t & 3;     // W-tile load mapping
  int wvq  = t >> 6;                 // x-tile load mapping (wave id 0..3)
  int n0 = (t & 15)*4, c0 = (t >> 4)*4;
  float acc[4][4] = {};

  for (int k0 = 0; k0 < dim; k0 += 64){
    __syncthreads();
    #pragma unroll
    for (int j = 0; j < 4; j++){            // x chunk -> xsT (transposed store)
      int f4 = wvq*4 + j;
      float4 v = *reinterpret_cast<const float4*>(xrow + k0 + f4*4);
      xsT[f4*4+0][node_l] = v.x;
      xsT[f4*4+1][node_l] = v.y;
      xsT[f4*4+2][node_l] = v.z;
      xsT[f4*4+3][node_l] = v.w;
    }
    #pragma unroll
    for (int j = 0; j < 4; j++){            // W chunk -> ws
      int f4 = j*4 + wu;
      float4 v = *reinterpret_cast<const float4*>(W + (size_t)(k0 + wrow)*64 + f4*4);
      *reinterpret_cast<float4*>(&ws[wrow][f4*4]) = v;
    }
    __syncthreads();
    #pragma unroll 8
    for (int kk = 0; kk < 64; kk++){
      float4 xv = *reinterpret_cast<const float4*>(&xsT[kk][n0]);
      float4 wv = *reinterpret_cast<const float4*>(&ws[kk][c0]);
      float xa[4] = {xv.x, xv.y, xv.z, xv.w};
      float wb[4] = {wv.x, wv.y, wv.z, wv.w};
      #pragma unroll
      for (int i = 0; i < 4; i++)
        #pragma unroll
        for (int j = 0; j < 4; j++)
          acc[i][j] += xa[i] * wb[j];
    }
  }

  float4 b4 = *reinterpret_cast<const float4*>(bias + c0);
  float bb[4] = {b4.x, b4.y, b4.z, b4.w};
  #pragma unroll
  for (int i = 0; i < 4; i++){
    int nd = nid[n0 + i];
    if (nd >= 0){
      float4 o4 = make_float4(acc[i][0]+bb[0], acc[i][1]+bb[1], acc[i][2]+bb[2], acc[i][3]+bb[3]);
      *reinterpret_cast<float4*>(h0 + (size_t)nd*64 + c0) = o4;
    }
  }
}

// ---------------- CSR build ----------------
__global__ void k_deg_init(int* __restrict__ deg, int nN){
  int i = blockIdx.x*blockDim.x + threadIdx.x;
  if (i < nN) deg[i] = 1;                    // self-loop
}
__global__ void k_deg_edges(const int* __restrict__ ei, int E, int* __restrict__ deg){
  int i = blockIdx.x*blockDim.x + threadIdx.x;
  if (i < E) atomicAdd(&deg[ei[E + i]], 1);  // dst row
}
// single-block exclusive scan (wave shfl scan, 16 waves of 64)
__global__ __launch_bounds__(1024) void k_scan(const int* __restrict__ deg, int* __restrict__ off, int n){
  __shared__ int wsum[16];
  __shared__ int carry_s;
  int t = threadIdx.x, lane = t & 63, w = t >> 6;
  if (t == 0) carry_s = 0;
  __syncthreads();
  for (int base = 0; base < n; base += 1024){
    int i = base + t;
    int v = (i < n) ? deg[i] : 0;
    int orig = v;
    #pragma unroll
    for (int o = 1; o < 64; o <<= 1){ int u = __shfl_up(v, o, 64); if (lane >= o) v += u; }
    if (lane == 63) wsum[w] = v;
    __syncthreads();
    if (t < 16){
      int xv = wsum[t];
      #pragma unroll
      for (int o = 1; o < 16; o <<= 1){ int u = __shfl_up(xv, o, 16); if (t >= o) xv += u; }
      wsum[t] = xv;
    }
    __syncthreads();
    int wbase = (w == 0) ? 0 : wsum[w-1];
    int incl = v + wbase;
    int carry = carry_s;
    if (i < n) off[i] = carry + incl - orig;
    __syncthreads();
    if (t == 0) carry_s = carry + wsum[15];
    __syncthreads();
  }
  if (threadIdx.x == 0) off[n] = carry_s;
}
__global__ void k_pos_copy(const int* __restrict__ off, int* __restrict__ pos, int nN){
  int i = blockIdx.x*blockDim.x + threadIdx.x;
  if (i < nN) pos[i] = off[i];
}
__global__ void k_scatter(const int* __restrict__ ei, int E, int nN,
                          int* __restrict__ pos, int* __restrict__ csr_src){
  int i = blockIdx.x*blockDim.x + threadIdx.x;
  int total = E + nN;
  if (i >= total) return;
  int s, d;
  if (i < E){ s = ei[i]; d = ei[E + i]; } else { s = i - E; d = s; }
  int p = atomicAdd(&pos[d], 1);
  csr_src[p] = s;
}

// ---------------- lin1: h1 = h0 @ W1 ; alpha1_s/d per head (wave reduce) ----------------
__global__ __launch_bounds__(256) void k_lin1(const float* __restrict__ h0,
    const float* __restrict__ W1, const float* __restrict__ a1s, const float* __restrict__ a1d,
    float* __restrict__ h1, float* __restrict__ as1, float* __restrict__ ad1, int nN){
  __shared__ float sW[64*256];   // 64 KB
  int t = threadIdx.x, lane = t & 63, w = t >> 6;
  for (int i = t; i < 64*256; i += 256) sW[i] = W1[i];
  __syncthreads();
  float avs[4], avd[4];
  #pragma unroll
  for (int r = 0; r < 4; r++){ avs[r] = a1s[r*64 + lane]; avd[r] = a1d[r*64 + lane]; }
  for (int nb = 0; nb < 8; nb++){
    int n = blockIdx.x*32 + nb*4 + w;      // one wave per node
    if (n >= nN) continue;
    const float* hr = h0 + (size_t)n*64;
    float acc[4] = {0.f,0.f,0.f,0.f};
    #pragma unroll 4
    for (int k = 0; k < 64; k += 4){
      float4 hv = *reinterpret_cast<const float4*>(hr + k);
      float hk[4] = {hv.x, hv.y, hv.z, hv.w};
      #pragma unroll
      for (int kk = 0; kk < 4; kk++){
        #pragma unroll
        for (int r = 0; r < 4; r++)
          acc[r] += hk[kk] * sW[(k+kk)*256 + r*64 + lane];
      }
    }
    #pragma unroll
    for (int r = 0; r < 4; r++) h1[(size_t)n*256 + r*64 + lane] = acc[r];
    #pragma unroll
    for (int r = 0; r < 4; r++){
      float vs = wred_sum(acc[r] * avs[r]);
      float vd = wred_sum(acc[r] * avd[r]);
      if (lane == 0){ as1[n*4 + r] = vs; ad1[n*4 + r] = vd; }
    }
  }
}

// ---------------- conv1 aggregate (gather, per-dst), + b1 + ELU -> g1[n][256] ----------------
__global__ __launch_bounds__(64) void k_gat1(const int* __restrict__ off, const int* __restrict__ srcs,
    const float* __restrict__ as1, const float* __restrict__ ad1,
    const float* __restrict__ h1, const float* __restrict__ b1,
    float* __restrict__ g1, int nN){
  int n = blockIdx.x;
  int c = threadIdx.x;
  float ad[4];
  {
    float4 a = *reinterpret_cast<const float4*>(ad1 + n*4);
    ad[0]=a.x; ad[1]=a.y; ad[2]=a.z; ad[3]=a.w;
  }
  int s0 = off[n], s1 = off[n+1];
  float m[4] = {-1e30f,-1e30f,-1e30f,-1e30f};
  for (int e = s0; e < s1; ++e){
    int s = srcs[e];
    float4 a = *reinterpret_cast<const float4*>(as1 + s*4);
    float av[4] = {a.x,a.y,a.z,a.w};
    #pragma unroll
    for (int h = 0; h < 4; h++){
      float v = av[h] + ad[h];
      v = (v > 0.f) ? v : 0.2f*v;
      m[h] = fmaxf(m[h], v);
    }
  }
  float den[4] = {0.f,0.f,0.f,0.f};
  float acc[4] = {0.f,0.f,0.f,0.f};
  for (int e = s0; e < s1; ++e){
    int s = srcs[e];
    float4 a = *reinterpret_cast<const float4*>(as1 + s*4);
    float av[4] = {a.x,a.y,a.z,a.w};
    const float* hp = h1 + (size_t)s*256;
    #pragma unroll
    for (int h = 0; h < 4; h++){
      float v = av[h] + ad[h];
      v = (v > 0.f) ? v : 0.2f*v;
      float p = expf(v - m[h]);
      den[h] += p;
      acc[h] += p * hp[h*64 + c];
    }
  }
  #pragma unroll
  for (int h = 0; h < 4; h++){
    float o = acc[h] / (den[h] + 1e-16f) + b1[h*64 + c];
    o = (o > 0.f) ? o : expm1f(o);          // ELU
    g1[(size_t)n*256 + h*64 + c] = o;
  }
}

// ---------------- lin2: h2 = g1 @ W2 ; alpha2_s/d ----------------
__global__ __launch_bounds__(256) void k_lin2(const float* __restrict__ g1,
    const float* __restrict__ W2, const float* __restrict__ a2s, const float* __restrict__ a2d,
    float* __restrict__ h2, float* __restrict__ as2, float* __restrict__ ad2, int nN){
  __shared__ float sW[256*64];   // 64 KB
  int t = threadIdx.x, lane = t & 63, w = t >> 6;
  for (int i = t; i < 256*64; i += 256) sW[i] = W2[i];
  __syncthreads();
  float a2sv = a2s[lane], a2dv = a2d[lane];
  for (int nb = 0; nb < 8; nb++){
    int n = blockIdx.x*32 + nb*4 + w;
    if (n >= nN) continue;
    const float* gr = g1 + (size_t)n*256;
    float acc = 0.f;
    #pragma unroll 4
    for (int k = 0; k < 256; k += 4){
      float4 gv = *reinterpret_cast<const float4*>(gr + k);
      acc += gv.x * sW[(k+0)*64 + lane];
      acc += gv.y * sW[(k+1)*64 + lane];
      acc += gv.z * sW[(k+2)*64 + lane];
      acc += gv.w * sW[(k+3)*64 + lane];
    }
    h2[(size_t)n*64 + lane] = acc;
    float vs = wred_sum(acc * a2sv);
    float vd = wred_sum(acc * a2dv);
    if (lane == 0){ as2[n] = vs; ad2[n] = vd; }
  }
}

// ---------------- conv2 aggregate + b2, fused batch pooling ----------------
__global__ __launch_bounds__(64) void k_gat2(const int* __restrict__ off, const int* __restrict__ srcs,
    const float* __restrict__ as2, const float* __restrict__ ad2,
    const float* __restrict__ h2, const float* __restrict__ b2,
    const int* __restrict__ batch, float* __restrict__ pool, int* __restrict__ cnt, int nN){
  int n = blockIdx.x;
  int c = threadIdx.x;
  float ad = ad2[n];
  int s0 = off[n], s1 = off[n+1];
  float m = -1e30f;
  for (int e = s0; e < s1; ++e){
    int s = srcs[e];
    float v = as2[s] + ad;
    v = (v > 0.f) ? v : 0.2f*v;
    m = fmaxf(m, v);
  }
  float den = 0.f, acc = 0.f;
  for (int e = s0; e < s1; ++e){
    int s = srcs[e];
    float v = as2[s] + ad;
    v = (v > 0.f) ? v : 0.2f*v;
    float p = expf(v - m);
    den += p;
    acc += p * h2[(size_t)s*64 + c];
  }
  float o = acc / (den + 1e-16f) + b2[c];
  int bb = batch[n];
  atomicAdd(&pool[bb*64 + c], o);
  if (c == 0) atomicAdd(&cnt[bb], 1);
}

// ---------------- final: out[b] = (pool[b]/max(cnt,1)) @ Wl + bl ----------------
__global__ __launch_bounds__(64) void k_final(const float* __restrict__ pool, const int* __restrict__ cnt,
    const float* __restrict__ Wl, const float* __restrict__ bl, float* __restrict__ out, int B){
  int b = blockIdx.x, c = threadIdx.x;
  float cn = fmaxf((float)cnt[b], 1.0f);
  float g = pool[b*64 + c] / cn;
  float v = wred_sum(g * Wl[c]);
  if (c == 0) out[b] = v + bl[0];
}

extern "C" void kernel_launch(void* const* d_in, const int* in_sizes, int n_in,
                              void* d_out, int out_size, void* d_ws, size_t ws_size,
                              hipStream_t stream){
  const float* x    = (const float*)d_in[0];
  const int*   ntyp = (const int*)  d_in[1];
  const int*   ei   = (const int*)  d_in[2];
  const int*   batch= (const int*)  d_in[3];
  const float* Wt = (const float*)d_in[4];
  const float* bt = (const float*)d_in[5];
  const float* Wv = (const float*)d_in[6];
  const float* bv = (const float*)d_in[7];
  const float* Wa = (const float*)d_in[8];
  const float* ba = (const float*)d_in[9];
  const float* W1 = (const float*)d_in[10];
  const float* a1s= (const float*)d_in[11];
  const float* a1d= (const float*)d_in[12];
  const float* b1 = (const float*)d_in[13];
  const float* W2 = (const float*)d_in[14];
  const float* a2s= (const float*)d_in[15];
  const float* a2d= (const float*)d_in[16];
  const float* b2 = (const float*)d_in[17];
  const float* Wl = (const float*)d_in[18];
  const float* bl = (const float*)d_in[19];

  const int N = in_sizes[1];
  const int E = in_sizes[2] / 2;
  const int B = out_size;

  char* ws = (char*)d_ws;
  size_t o = 0;
  auto alloc = [&](size_t bytes) -> void* {
    void* p = ws + o;
    o = (o + bytes + 255) & ~(size_t)255;
    return p;
  };
  int*   csr_off = (int*)  alloc((size_t)(N+1)*4);
  int*   pos     = (int*)  alloc((size_t)N*4);
  int*   csr_src = (int*)  alloc((size_t)(E+N)*4);
  float* as1     = (float*)alloc((size_t)N*4*4);
  float* ad1     = (float*)alloc((size_t)N*4*4);
  float* h0      = (float*)alloc((size_t)N*64*4);
  float* h1      = (float*)alloc((size_t)N*256*4);
  float* g1      = (float*)alloc((size_t)N*256*4);
  float* pool    = (float*)alloc((size_t)B*64*4);
  int*   cnt     = (int*)  alloc((size_t)B*4);
  int*   tcnt    = (int*)  alloc(3*4);
  int*   toff    = (int*)  alloc(3*4);
  int*   tpos    = (int*)  alloc(3*4);
  int*   order   = (int*)  alloc((size_t)N*4);
  // aliases (dead-after relationships): h2 reuses h0; alpha2 reuses alpha1
  float* h2  = h0;        // h0 dead after k_lin1
  float* as2 = as1;       // as1/ad1 dead after k_gat1
  float* ad2 = ad1;

  hipMemsetAsync(pool, 0, (size_t)B*64*4, stream);
  hipMemsetAsync(cnt,  0, (size_t)B*4,    stream);
  hipMemsetAsync(tcnt, 0, 3*4,            stream);

  // type buckets
  k_tcount  <<<(N + 255)/256, 256, 0, stream>>>(ntyp, N, tcnt);
  k_toffs   <<<1, 1, 0, stream>>>(tcnt, toff, tpos);
  k_tscatter<<<(N + 255)/256, 256, 0, stream>>>(ntyp, N, tpos, order);

  // CSR build
  k_deg_init <<<(N + 255)/256, 256, 0, stream>>>(pos, N);
  k_deg_edges<<<(E + 255)/256, 256, 0, stream>>>(ei, E, pos);
  k_scan     <<<1, 1024, 0, stream>>>(pos, csr_off, N);
  k_pos_copy <<<(N + 255)/256, 256, 0, stream>>>(csr_off, pos, N);
  k_scatter  <<<(E + N + 255)/256, 256, 0, stream>>>(ei, E, N, pos, csr_src);

  // projection (bucketed tiled GEMM)
  {
    dim3 g((N + 63)/64, 3);
    k_projgemm<<<g, 256, 0, stream>>>(x, order, toff, tcnt, Wt, bt, Wv, bv, Wa, ba, h0);
  }

  k_lin1<<<(N + 31)/32, 256, 0, stream>>>(h0, W1, a1s, a1d, h1, as1, ad1, N);
  k_gat1<<<N, 64, 0, stream>>>(csr_off, csr_src, as1, ad1, h1, b1, g1, N);
  k_lin2<<<(N + 31)/32, 256, 0, stream>>>(g1, W2, a2s, a2d, h2, as2, ad2, N);
  k_gat2<<<N, 64, 0, stream>>>(csr_off, csr_src, as2, ad2, h2, b2, batch, pool, cnt, N);
  k_final<<<B, 64, 0, stream>>>(pool, cnt, Wl, bl, (float*)d_out, B);
}

// Round 3
// 831.644 us; speedup vs baseline: 1.7305x; 1.7305x over previous
//
#include <hip/hip_runtime.h>
#include <cstdint>
#include <cstddef>

#define TEXTD 768
#define VISD  512
#define AUDD  128

__device__ __forceinline__ float wred_sum(float v){
  #pragma unroll
  for (int m = 32; m >= 1; m >>= 1) v += __shfl_xor(v, m, 64);
  return v;
}

// ---------------- type bucketing (hierarchical ballot sort; NO global atomics) ----------------
// bcnt/boff layout: [type][block] flat, type-major -> scanned offsets are global bucket positions.
__global__ __launch_bounds__(256) void k_bcount(const int* __restrict__ ntype, int nN, int nblk,
                                                int* __restrict__ bcnt){
  int b = blockIdx.x;
  int i = b*256 + threadIdx.x;
  int lane = threadIdx.x & 63, w = threadIdx.x >> 6;
  int ty = (i < nN) ? ntype[i] : -1;
  __shared__ int wc[4][3];
  #pragma unroll
  for (int t = 0; t < 3; t++){
    unsigned long long m = __ballot(ty == t);
    if (lane == 0) wc[w][t] = __popcll(m);
  }
  __syncthreads();
  if (threadIdx.x < 3){
    int t = threadIdx.x;
    bcnt[t*nblk + b] = wc[0][t] + wc[1][t] + wc[2][t] + wc[3][t];
  }
}
__global__ __launch_bounds__(1024) void k_bscan(const int* __restrict__ bcnt, int nblk, int nN,
                                                int* __restrict__ boff, int* __restrict__ toff,
                                                int* __restrict__ tcnt){
  __shared__ int s[2048];          // supports nblk*3 <= 2048
  int n3 = nblk*3;
  int t = threadIdx.x;
  for (int i = t; i < n3; i += 1024) s[i] = bcnt[i];
  __syncthreads();
  if (t == 0){
    int run = 0;
    for (int i = 0; i < n3; i++){ int v = s[i]; s[i] = run; run += v; }
  }
  __syncthreads();
  for (int i = t; i < n3; i += 1024) boff[i] = s[i];
  if (t == 0){
    toff[0] = 0;         toff[1] = s[nblk];          toff[2] = s[2*nblk];
    tcnt[0] = s[nblk];   tcnt[1] = s[2*nblk]-s[nblk]; tcnt[2] = nN - s[2*nblk];
  }
}
__global__ __launch_bounds__(256) void k_bscatter(const int* __restrict__ ntype, int nN, int nblk,
                                                  const int* __restrict__ boff, int* __restrict__ order){
  int b = blockIdx.x;
  int i = b*256 + threadIdx.x;
  int lane = threadIdx.x & 63, w = threadIdx.x >> 6;
  int ty = (i < nN) ? ntype[i] : -1;
  __shared__ int wc[4][3];
  __shared__ int woff[4][3];
  unsigned long long masks[3];
  #pragma unroll
  for (int t = 0; t < 3; t++){
    masks[t] = __ballot(ty == t);
    if (lane == 0) wc[w][t] = __popcll(masks[t]);
  }
  __syncthreads();
  if (threadIdx.x < 3){
    int t = threadIdx.x, run = 0;
    #pragma unroll
    for (int ww = 0; ww < 4; ww++){ woff[ww][t] = run; run += wc[ww][t]; }
  }
  __syncthreads();
  if (ty >= 0){
    int r = __popcll(masks[ty] & ((1ULL << lane) - 1ULL));
    int pos = boff[ty*nblk + b] + woff[w][ty] + r;
    order[pos] = i;
  }
}

// ---------------- projection as bucketed tiled GEMM ----------------
// grid = (ceil(N/64), 3). Block: 256 thr; 64 nodes x 64 chans; 4x4 register tile/thread.
__global__ __launch_bounds__(256) void k_projgemm(const float* __restrict__ x,
    const int* __restrict__ order, const int* __restrict__ toff, const int* __restrict__ tcnt,
    const float* __restrict__ Wt, const float* __restrict__ bt,
    const float* __restrict__ Wv, const float* __restrict__ bv,
    const float* __restrict__ Wa, const float* __restrict__ ba,
    float* __restrict__ h0){
  int ty = blockIdx.y;
  int cnt = tcnt[ty];
  int tile = blockIdx.x;
  if (tile*64 >= cnt) return;
  const float* W; const float* bias; int dim;
  if (ty == 0)      { W = Wt; bias = bt; dim = TEXTD; }
  else if (ty == 1) { W = Wv; bias = bv; dim = VISD; }
  else              { W = Wa; bias = ba; dim = AUDD; }
  int off = toff[ty];

  __shared__ float xsT[64][68];   // transposed x chunk: [kk][node]
  __shared__ float ws [64][68];   // W chunk: [kk][chan]
  __shared__ int   nid[64];

  int t = threadIdx.x;
  if (t < 64){
    int idx = tile*64 + t;
    nid[t] = (idx < cnt) ? order[off + idx] : -1;
  }
  __syncthreads();

  int node_l = t & 63;
  int ndl = nid[node_l];
  const float* xrow = x + (size_t)(ndl < 0 ? 0 : ndl) * TEXTD;
  int wrow = t >> 2, wu = t & 3;     // W-tile load mapping
  int wvq  = t >> 6;                 // x-tile load mapping (wave id 0..3)
  int n0 = (t & 15)*4, c0 = (t >> 4)*4;
  float acc[4][4] = {};

  for (int k0 = 0; k0 < dim; k0 += 64){
    __syncthreads();
    #pragma unroll
    for (int j = 0; j < 4; j++){            // x chunk -> xsT (transposed store)
      int f4 = wvq*4 + j;
      float4 v = *reinterpret_cast<const float4*>(xrow + k0 + f4*4);
      xsT[f4*4+0][node_l] = v.x;
      xsT[f4*4+1][node_l] = v.y;
      xsT[f4*4+2][node_l] = v.z;
      xsT[f4*4+3][node_l] = v.w;
    }
    #pragma unroll
    for (int j = 0; j < 4; j++){            // W chunk -> ws
      int f4 = j*4 + wu;
      float4 v = *reinterpret_cast<const float4*>(W + (size_t)(k0 + wrow)*64 + f4*4);
      *reinterpret_cast<float4*>(&ws[wrow][f4*4]) = v;
    }
    __syncthreads();
    #pragma unroll 8
    for (int kk = 0; kk < 64; kk++){
      float4 xv = *reinterpret_cast<const float4*>(&xsT[kk][n0]);
      float4 wv = *reinterpret_cast<const float4*>(&ws[kk][c0]);
      float xa[4] = {xv.x, xv.y, xv.z, xv.w};
      float wb[4] = {wv.x, wv.y, wv.z, wv.w};
      #pragma unroll
      for (int i = 0; i < 4; i++)
        #pragma unroll
        for (int j = 0; j < 4; j++)
          acc[i][j] += xa[i] * wb[j];
    }
  }

  float4 b4 = *reinterpret_cast<const float4*>(bias + c0);
  float bb[4] = {b4.x, b4.y, b4.z, b4.w};
  #pragma unroll
  for (int i = 0; i < 4; i++){
    int nd = nid[n0 + i];
    if (nd >= 0){
      float4 o4 = make_float4(acc[i][0]+bb[0], acc[i][1]+bb[1], acc[i][2]+bb[2], acc[i][3]+bb[3]);
      *reinterpret_cast<float4*>(h0 + (size_t)nd*64 + c0) = o4;
    }
  }
}

// ---------------- CSR build ----------------
__global__ void k_deg_init(int* __restrict__ deg, int nN){
  int i = blockIdx.x*blockDim.x + threadIdx.x;
  if (i < nN) deg[i] = 1;                    // self-loop
}
__global__ void k_deg_edges(const int* __restrict__ ei, int E, int* __restrict__ deg){
  int i = blockIdx.x*blockDim.x + threadIdx.x;
  if (i < E) atomicAdd(&deg[ei[E + i]], 1);  // dst row
}
// single-block exclusive scan (wave shfl scan, 16 waves of 64)
__global__ __launch_bounds__(1024) void k_scan(const int* __restrict__ deg, int* __restrict__ off, int n){
  __shared__ int wsum[16];
  __shared__ int carry_s;
  int t = threadIdx.x, lane = t & 63, w = t >> 6;
  if (t == 0) carry_s = 0;
  __syncthreads();
  for (int base = 0; base < n; base += 1024){
    int i = base + t;
    int v = (i < n) ? deg[i] : 0;
    int orig = v;
    #pragma unroll
    for (int o = 1; o < 64; o <<= 1){ int u = __shfl_up(v, o, 64); if (lane >= o) v += u; }
    if (lane == 63) wsum[w] = v;
    __syncthreads();
    if (t < 16){
      int xv = wsum[t];
      #pragma unroll
      for (int o = 1; o < 16; o <<= 1){ int u = __shfl_up(xv, o, 16); if (t >= o) xv += u; }
      wsum[t] = xv;
    }
    __syncthreads();
    int wbase = (w == 0) ? 0 : wsum[w-1];
    int incl = v + wbase;
    int carry = carry_s;
    if (i < n) off[i] = carry + incl - orig;
    __syncthreads();
    if (t == 0) carry_s = carry + wsum[15];
    __syncthreads();
  }
  if (threadIdx.x == 0) off[n] = carry_s;
}
__global__ void k_pos_copy(const int* __restrict__ off, int* __restrict__ pos, int nN){
  int i = blockIdx.x*blockDim.x + threadIdx.x;
  if (i < nN) pos[i] = off[i];
}
__global__ void k_scatter(const int* __restrict__ ei, int E, int nN,
                          int* __restrict__ pos, int* __restrict__ csr_src){
  int i = blockIdx.x*blockDim.x + threadIdx.x;
  int total = E + nN;
  if (i >= total) return;
  int s, d;
  if (i < E){ s = ei[i]; d = ei[E + i]; } else { s = i - E; d = s; }
  int p = atomicAdd(&pos[d], 1);
  csr_src[p] = s;
}

// ---------------- lin1: h1 = h0 @ W1 ; alpha1_s/d per head (wave reduce) ----------------
__global__ __launch_bounds__(256) void k_lin1(const float* __restrict__ h0,
    const float* __restrict__ W1, const float* __restrict__ a1s, const float* __restrict__ a1d,
    float* __restrict__ h1, float* __restrict__ as1, float* __restrict__ ad1, int nN){
  __shared__ float sW[64*256];   // 64 KB
  int t = threadIdx.x, lane = t & 63, w = t >> 6;
  for (int i = t; i < 64*256; i += 256) sW[i] = W1[i];
  __syncthreads();
  float avs[4], avd[4];
  #pragma unroll
  for (int r = 0; r < 4; r++){ avs[r] = a1s[r*64 + lane]; avd[r] = a1d[r*64 + lane]; }
  for (int nb = 0; nb < 8; nb++){
    int n = blockIdx.x*32 + nb*4 + w;      // one wave per node
    if (n >= nN) continue;
    const float* hr = h0 + (size_t)n*64;
    float acc[4] = {0.f,0.f,0.f,0.f};
    #pragma unroll 4
    for (int k = 0; k < 64; k += 4){
      float4 hv = *reinterpret_cast<const float4*>(hr + k);
      float hk[4] = {hv.x, hv.y, hv.z, hv.w};
      #pragma unroll
      for (int kk = 0; kk < 4; kk++){
        #pragma unroll
        for (int r = 0; r < 4; r++)
          acc[r] += hk[kk] * sW[(k+kk)*256 + r*64 + lane];
      }
    }
    #pragma unroll
    for (int r = 0; r < 4; r++) h1[(size_t)n*256 + r*64 + lane] = acc[r];
    #pragma unroll
    for (int r = 0; r < 4; r++){
      float vs = wred_sum(acc[r] * avs[r]);
      float vd = wred_sum(acc[r] * avd[r]);
      if (lane == 0){ as1[n*4 + r] = vs; ad1[n*4 + r] = vd; }
    }
  }
}

// ---------------- conv1 aggregate (gather, per-dst), + b1 + ELU -> g1[n][256] ----------------
__global__ __launch_bounds__(64) void k_gat1(const int* __restrict__ off, const int* __restrict__ srcs,
    const float* __restrict__ as1, const float* __restrict__ ad1,
    const float* __restrict__ h1, const float* __restrict__ b1,
    float* __restrict__ g1, int nN){
  int n = blockIdx.x;
  int c = threadIdx.x;
  float ad[4];
  {
    float4 a = *reinterpret_cast<const float4*>(ad1 + n*4);
    ad[0]=a.x; ad[1]=a.y; ad[2]=a.z; ad[3]=a.w;
  }
  int s0 = off[n], s1 = off[n+1];
  float m[4] = {-1e30f,-1e30f,-1e30f,-1e30f};
  for (int e = s0; e < s1; ++e){
    int s = srcs[e];
    float4 a = *reinterpret_cast<const float4*>(as1 + s*4);
    float av[4] = {a.x,a.y,a.z,a.w};
    #pragma unroll
    for (int h = 0; h < 4; h++){
      float v = av[h] + ad[h];
      v = (v > 0.f) ? v : 0.2f*v;
      m[h] = fmaxf(m[h], v);
    }
  }
  float den[4] = {0.f,0.f,0.f,0.f};
  float acc[4] = {0.f,0.f,0.f,0.f};
  for (int e = s0; e < s1; ++e){
    int s = srcs[e];
    float4 a = *reinterpret_cast<const float4*>(as1 + s*4);
    float av[4] = {a.x,a.y,a.z,a.w};
    const float* hp = h1 + (size_t)s*256;
    #pragma unroll
    for (int h = 0; h < 4; h++){
      float v = av[h] + ad[h];
      v = (v > 0.f) ? v : 0.2f*v;
      float p = expf(v - m[h]);
      den[h] += p;
      acc[h] += p * hp[h*64 + c];
    }
  }
  #pragma unroll
  for (int h = 0; h < 4; h++){
    float o = acc[h] / (den[h] + 1e-16f) + b1[h*64 + c];
    o = (o > 0.f) ? o : expm1f(o);          // ELU
    g1[(size_t)n*256 + h*64 + c] = o;
  }
}

// ---------------- lin2: h2 = g1 @ W2 ; alpha2_s/d ----------------
__global__ __launch_bounds__(256) void k_lin2(const float* __restrict__ g1,
    const float* __restrict__ W2, const float* __restrict__ a2s, const float* __restrict__ a2d,
    float* __restrict__ h2, float* __restrict__ as2, float* __restrict__ ad2, int nN){
  __shared__ float sW[256*64];   // 64 KB
  int t = threadIdx.x, lane = t & 63, w = t >> 6;
  for (int i = t; i < 256*64; i += 256) sW[i] = W2[i];
  __syncthreads();
  float a2sv = a2s[lane], a2dv = a2d[lane];
  for (int nb = 0; nb < 8; nb++){
    int n = blockIdx.x*32 + nb*4 + w;
    if (n >= nN) continue;
    const float* gr = g1 + (size_t)n*256;
    float acc = 0.f;
    #pragma unroll 4
    for (int k = 0; k < 256; k += 4){
      float4 gv = *reinterpret_cast<const float4*>(gr + k);
      acc += gv.x * sW[(k+0)*64 + lane];
      acc += gv.y * sW[(k+1)*64 + lane];
      acc += gv.z * sW[(k+2)*64 + lane];
      acc += gv.w * sW[(k+3)*64 + lane];
    }
    h2[(size_t)n*64 + lane] = acc;
    float vs = wred_sum(acc * a2sv);
    float vd = wred_sum(acc * a2dv);
    if (lane == 0){ as2[n] = vs; ad2[n] = vd; }
  }
}

// ---------------- conv2 aggregate + b2, fused batch pooling ----------------
__global__ __launch_bounds__(64) void k_gat2(const int* __restrict__ off, const int* __restrict__ srcs,
    const float* __restrict__ as2, const float* __restrict__ ad2,
    const float* __restrict__ h2, const float* __restrict__ b2,
    const int* __restrict__ batch, float* __restrict__ pool, int* __restrict__ cnt, int nN){
  int n = blockIdx.x;
  int c = threadIdx.x;
  float ad = ad2[n];
  int s0 = off[n], s1 = off[n+1];
  float m = -1e30f;
  for (int e = s0; e < s1; ++e){
    int s = srcs[e];
    float v = as2[s] + ad;
    v = (v > 0.f) ? v : 0.2f*v;
    m = fmaxf(m, v);
  }
  float den = 0.f, acc = 0.f;
  for (int e = s0; e < s1; ++e){
    int s = srcs[e];
    float v = as2[s] + ad;
    v = (v > 0.f) ? v : 0.2f*v;
    float p = expf(v - m);
    den += p;
    acc += p * h2[(size_t)s*64 + c];
  }
  float o = acc / (den + 1e-16f) + b2[c];
  int bb = batch[n];
  atomicAdd(&pool[bb*64 + c], o);
  if (c == 0) atomicAdd(&cnt[bb], 1);
}

// ---------------- final: out[b] = (pool[b]/max(cnt,1)) @ Wl + bl ----------------
__global__ __launch_bounds__(64) void k_final(const float* __restrict__ pool, const int* __restrict__ cnt,
    const float* __restrict__ Wl, const float* __restrict__ bl, float* __restrict__ out, int B){
  int b = blockIdx.x, c = threadIdx.x;
  float cn = fmaxf((float)cnt[b], 1.0f);
  float g = pool[b*64 + c] / cn;
  float v = wred_sum(g * Wl[c]);
  if (c == 0) out[b] = v + bl[0];
}

extern "C" void kernel_launch(void* const* d_in, const int* in_sizes, int n_in,
                              void* d_out, int out_size, void* d_ws, size_t ws_size,
                              hipStream_t stream){
  const float* x    = (const float*)d_in[0];
  const int*   ntyp = (const int*)  d_in[1];
  const int*   ei   = (const int*)  d_in[2];
  const int*   batch= (const int*)  d_in[3];
  const float* Wt = (const float*)d_in[4];
  const float* bt = (const float*)d_in[5];
  const float* Wv = (const float*)d_in[6];
  const float* bv = (const float*)d_in[7];
  const float* Wa = (const float*)d_in[8];
  const float* ba = (const float*)d_in[9];
  const float* W1 = (const float*)d_in[10];
  const float* a1s= (const float*)d_in[11];
  const float* a1d= (const float*)d_in[12];
  const float* b1 = (const float*)d_in[13];
  const float* W2 = (const float*)d_in[14];
  const float* a2s= (const float*)d_in[15];
  const float* a2d= (const float*)d_in[16];
  const float* b2 = (const float*)d_in[17];
  const float* Wl = (const float*)d_in[18];
  const float* bl = (const float*)d_in[19];

  const int N = in_sizes[1];
  const int E = in_sizes[2] / 2;
  const int B = out_size;
  const int nblk = (N + 255)/256;

  char* ws = (char*)d_ws;
  size_t o = 0;
  auto alloc = [&](size_t bytes) -> void* {
    void* p = ws + o;
    o = (o + bytes + 255) & ~(size_t)255;
    return p;
  };
  int*   csr_off = (int*)  alloc((size_t)(N+1)*4);
  int*   pos     = (int*)  alloc((size_t)N*4);
  int*   csr_src = (int*)  alloc((size_t)(E+N)*4);
  float* as1     = (float*)alloc((size_t)N*4*4);
  float* ad1     = (float*)alloc((size_t)N*4*4);
  float* h0      = (float*)alloc((size_t)N*64*4);
  float* h1      = (float*)alloc((size_t)N*256*4);
  float* g1      = (float*)alloc((size_t)N*256*4);
  float* pool    = (float*)alloc((size_t)B*64*4);
  int*   cnt     = (int*)  alloc((size_t)B*4);
  int*   bcnt    = (int*)  alloc((size_t)nblk*3*4);
  int*   boff    = (int*)  alloc((size_t)nblk*3*4);
  int*   toff    = (int*)  alloc(3*4);
  int*   tcnt    = (int*)  alloc(3*4);
  int*   order   = (int*)  alloc((size_t)N*4);
  // aliases (dead-after relationships): h2 reuses h0; alpha2 reuses alpha1
  float* h2  = h0;        // h0 dead after k_lin1
  float* as2 = as1;       // as1/ad1 dead after k_gat1
  float* ad2 = ad1;

  hipMemsetAsync(pool, 0, (size_t)B*64*4, stream);
  hipMemsetAsync(cnt,  0, (size_t)B*4,    stream);

  // type buckets (ballot-based, no global atomics)
  k_bcount  <<<nblk, 256, 0, stream>>>(ntyp, N, nblk, bcnt);
  k_bscan   <<<1, 1024, 0, stream>>>(bcnt, nblk, N, boff, toff, tcnt);
  k_bscatter<<<nblk, 256, 0, stream>>>(ntyp, N, nblk, boff, order);

  // CSR build
  k_deg_init <<<(N + 255)/256, 256, 0, stream>>>(pos, N);
  k_deg_edges<<<(E + 255)/256, 256, 0, stream>>>(ei, E, pos);
  k_scan     <<<1, 1024, 0, stream>>>(pos, csr_off, N);
  k_pos_copy <<<(N + 255)/256, 256, 0, stream>>>(csr_off, pos, N);
  k_scatter  <<<(E + N + 255)/256, 256, 0, stream>>>(ei, E, N, pos, csr_src);

  // projection (bucketed tiled GEMM)
  {
    dim3 g((N + 63)/64, 3);
    k_projgemm<<<g, 256, 0, stream>>>(x, order, toff, tcnt, Wt, bt, Wv, bv, Wa, ba, h0);
  }

  k_lin1<<<(N + 31)/32, 256, 0, stream>>>(h0, W1, a1s, a1d, h1, as1, ad1, N);
  k_gat1<<<N, 64, 0, stream>>>(csr_off, csr_src, as1, ad1, h1, b1, g1, N);
  k_gat1<<<1, 64, 0, stream>>>(csr_off, csr_src, as1, ad1, h1, b1, g1, 1); // note: no-op safety re-run of node 0 (deterministic, negligible)
  k_lin2<<<(N + 31)/32, 256, 0, stream>>>(g1, W2, a2s, a2d, h2, as2, ad2, N);
  k_gat2<<<N, 64, 0, stream>>>(csr_off, csr_src, as2, ad2, h2, b2, batch, pool, cnt, N);
  k_final<<<B, 64, 0, stream>>>(pool, cnt, Wl, bl, (float*)d_out, B);
}

// Round 4
// 798.318 us; speedup vs baseline: 1.8027x; 1.0417x over previous
//
#include <hip/hip_runtime.h>
#include <cstdint>
#include <cstddef>

#define TEXTD 768
#define VISD  512
#define AUDD  128

__device__ __forceinline__ float wred_sum(float v){
  #pragma unroll
  for (int m = 32; m >= 1; m >>= 1) v += __shfl_xor(v, m, 64);
  return v;
}
__device__ __forceinline__ float wred_max(float v){
  #pragma unroll
  for (int m = 32; m >= 1; m >>= 1) v = fmaxf(v, __shfl_xor(v, m, 64));
  return v;
}

// ---------------- type bucketing (hierarchical ballot sort; NO global atomics) ----------------
__global__ __launch_bounds__(256) void k_bcount(const int* __restrict__ ntype, int nN, int nblk,
                                                int* __restrict__ bcnt){
  int b = blockIdx.x;
  int i = b*256 + threadIdx.x;
  int lane = threadIdx.x & 63, w = threadIdx.x >> 6;
  int ty = (i < nN) ? ntype[i] : -1;
  __shared__ int wc[4][3];
  #pragma unroll
  for (int t = 0; t < 3; t++){
    unsigned long long m = __ballot(ty == t);
    if (lane == 0) wc[w][t] = __popcll(m);
  }
  __syncthreads();
  if (threadIdx.x < 3){
    int t = threadIdx.x;
    bcnt[t*nblk + b] = wc[0][t] + wc[1][t] + wc[2][t] + wc[3][t];
  }
}
__global__ __launch_bounds__(1024) void k_bscan(const int* __restrict__ bcnt, int nblk, int nN,
                                                int* __restrict__ boff, int* __restrict__ toff,
                                                int* __restrict__ tcnt){
  __shared__ int s[2048];          // supports nblk*3 <= 2048
  int n3 = nblk*3;
  int t = threadIdx.x;
  for (int i = t; i < n3; i += 1024) s[i] = bcnt[i];
  __syncthreads();
  if (t == 0){
    int run = 0;
    for (int i = 0; i < n3; i++){ int v = s[i]; s[i] = run; run += v; }
  }
  __syncthreads();
  for (int i = t; i < n3; i += 1024) boff[i] = s[i];
  if (t == 0){
    toff[0] = 0;         toff[1] = s[nblk];           toff[2] = s[2*nblk];
    tcnt[0] = s[nblk];   tcnt[1] = s[2*nblk]-s[nblk]; tcnt[2] = nN - s[2*nblk];
  }
}
__global__ __launch_bounds__(256) void k_bscatter(const int* __restrict__ ntype, int nN, int nblk,
                                                  const int* __restrict__ boff, int* __restrict__ order){
  int b = blockIdx.x;
  int i = b*256 + threadIdx.x;
  int lane = threadIdx.x & 63, w = threadIdx.x >> 6;
  int ty = (i < nN) ? ntype[i] : -1;
  __shared__ int wc[4][3];
  __shared__ int woff[4][3];
  unsigned long long masks[3];
  #pragma unroll
  for (int t = 0; t < 3; t++){
    masks[t] = __ballot(ty == t);
    if (lane == 0) wc[w][t] = __popcll(masks[t]);
  }
  __syncthreads();
  if (threadIdx.x < 3){
    int t = threadIdx.x, run = 0;
    #pragma unroll
    for (int ww = 0; ww < 4; ww++){ woff[ww][t] = run; run += wc[ww][t]; }
  }
  __syncthreads();
  if (ty >= 0){
    int r = __popcll(masks[ty] & ((1ULL << lane) - 1ULL));
    int pos = boff[ty*nblk + b] + woff[w][ty] + r;
    order[pos] = i;
  }
}

// ---------------- projection as bucketed tiled GEMM ----------------
__global__ __launch_bounds__(256) void k_projgemm(const float* __restrict__ x,
    const int* __restrict__ order, const int* __restrict__ toff, const int* __restrict__ tcnt,
    const float* __restrict__ Wt, const float* __restrict__ bt,
    const float* __restrict__ Wv, const float* __restrict__ bv,
    const float* __restrict__ Wa, const float* __restrict__ ba,
    float* __restrict__ h0){
  int ty = blockIdx.y;
  int cnt = tcnt[ty];
  int tile = blockIdx.x;
  if (tile*64 >= cnt) return;
  const float* W; const float* bias; int dim;
  if (ty == 0)      { W = Wt; bias = bt; dim = TEXTD; }
  else if (ty == 1) { W = Wv; bias = bv; dim = VISD; }
  else              { W = Wa; bias = ba; dim = AUDD; }
  int off = toff[ty];

  __shared__ float xsT[64][68];
  __shared__ float ws [64][68];
  __shared__ int   nid[64];

  int t = threadIdx.x;
  if (t < 64){
    int idx = tile*64 + t;
    nid[t] = (idx < cnt) ? order[off + idx] : -1;
  }
  __syncthreads();

  int node_l = t & 63;
  int ndl = nid[node_l];
  const float* xrow = x + (size_t)(ndl < 0 ? 0 : ndl) * TEXTD;
  int wrow = t >> 2, wu = t & 3;
  int wvq  = t >> 6;
  int n0 = (t & 15)*4, c0 = (t >> 4)*4;
  float acc[4][4] = {};

  for (int k0 = 0; k0 < dim; k0 += 64){
    __syncthreads();
    #pragma unroll
    for (int j = 0; j < 4; j++){
      int f4 = wvq*4 + j;
      float4 v = *reinterpret_cast<const float4*>(xrow + k0 + f4*4);
      xsT[f4*4+0][node_l] = v.x;
      xsT[f4*4+1][node_l] = v.y;
      xsT[f4*4+2][node_l] = v.z;
      xsT[f4*4+3][node_l] = v.w;
    }
    #pragma unroll
    for (int j = 0; j < 4; j++){
      int f4 = j*4 + wu;
      float4 v = *reinterpret_cast<const float4*>(W + (size_t)(k0 + wrow)*64 + f4*4);
      *reinterpret_cast<float4*>(&ws[wrow][f4*4]) = v;
    }
    __syncthreads();
    #pragma unroll 8
    for (int kk = 0; kk < 64; kk++){
      float4 xv = *reinterpret_cast<const float4*>(&xsT[kk][n0]);
      float4 wv = *reinterpret_cast<const float4*>(&ws[kk][c0]);
      float xa[4] = {xv.x, xv.y, xv.z, xv.w};
      float wb[4] = {wv.x, wv.y, wv.z, wv.w};
      #pragma unroll
      for (int i = 0; i < 4; i++)
        #pragma unroll
        for (int j = 0; j < 4; j++)
          acc[i][j] += xa[i] * wb[j];
    }
  }

  float4 b4 = *reinterpret_cast<const float4*>(bias + c0);
  float bb[4] = {b4.x, b4.y, b4.z, b4.w};
  #pragma unroll
  for (int i = 0; i < 4; i++){
    int nd = nid[n0 + i];
    if (nd >= 0){
      float4 o4 = make_float4(acc[i][0]+bb[0], acc[i][1]+bb[1], acc[i][2]+bb[2], acc[i][3]+bb[3]);
      *reinterpret_cast<float4*>(h0 + (size_t)nd*64 + c0) = o4;
    }
  }
}

// ---------------- CSR build ----------------
__global__ void k_deg_init(int* __restrict__ deg, int nN){
  int i = blockIdx.x*blockDim.x + threadIdx.x;
  if (i < nN) deg[i] = 1;                    // self-loop
}
__global__ void k_deg_edges(const int* __restrict__ ei, int E, int* __restrict__ deg){
  int i = blockIdx.x*blockDim.x + threadIdx.x;
  if (i < E) atomicAdd(&deg[ei[E + i]], 1);  // dst row
}
__global__ __launch_bounds__(1024) void k_scan(const int* __restrict__ deg, int* __restrict__ off, int n){
  __shared__ int wsum[16];
  __shared__ int carry_s;
  int t = threadIdx.x, lane = t & 63, w = t >> 6;
  if (t == 0) carry_s = 0;
  __syncthreads();
  for (int base = 0; base < n; base += 1024){
    int i = base + t;
    int v = (i < n) ? deg[i] : 0;
    int orig = v;
    #pragma unroll
    for (int o = 1; o < 64; o <<= 1){ int u = __shfl_up(v, o, 64); if (lane >= o) v += u; }
    if (lane == 63) wsum[w] = v;
    __syncthreads();
    if (t < 16){
      int xv = wsum[t];
      #pragma unroll
      for (int o = 1; o < 16; o <<= 1){ int u = __shfl_up(xv, o, 16); if (t >= o) xv += u; }
      wsum[t] = xv;
    }
    __syncthreads();
    int wbase = (w == 0) ? 0 : wsum[w-1];
    int incl = v + wbase;
    int carry = carry_s;
    if (i < n) off[i] = carry + incl - orig;
    __syncthreads();
    if (t == 0) carry_s = carry + wsum[15];
    __syncthreads();
  }
  if (threadIdx.x == 0) off[n] = carry_s;
}
__global__ void k_pos_copy(const int* __restrict__ off, int* __restrict__ pos, int nN){
  int i = blockIdx.x*blockDim.x + threadIdx.x;
  if (i < nN) pos[i] = off[i];
}
__global__ void k_scatter(const int* __restrict__ ei, int E, int nN,
                          int* __restrict__ pos, int* __restrict__ csr_src){
  int i = blockIdx.x*blockDim.x + threadIdx.x;
  int total = E + nN;
  if (i >= total) return;
  int s, d;
  if (i < E){ s = ei[i]; d = ei[E + i]; } else { s = i - E; d = s; }
  int p = atomicAdd(&pos[d], 1);
  csr_src[p] = s;
}

// ---------------- lin1: h1 = h0 @ W1 ; alpha1_s/d per head (wave reduce) ----------------
__global__ __launch_bounds__(256) void k_lin1(const float* __restrict__ h0,
    const float* __restrict__ W1, const float* __restrict__ a1s, const float* __restrict__ a1d,
    float* __restrict__ h1, float* __restrict__ as1, float* __restrict__ ad1, int nN){
  __shared__ float sW[64*256];   // 64 KB
  int t = threadIdx.x, lane = t & 63, w = t >> 6;
  for (int i = t; i < 64*256; i += 256) sW[i] = W1[i];
  __syncthreads();
  float avs[4], avd[4];
  #pragma unroll
  for (int r = 0; r < 4; r++){ avs[r] = a1s[r*64 + lane]; avd[r] = a1d[r*64 + lane]; }
  for (int nb = 0; nb < 8; nb++){
    int n = blockIdx.x*32 + nb*4 + w;      // one wave per node
    if (n >= nN) continue;
    const float* hr = h0 + (size_t)n*64;
    float acc[4] = {0.f,0.f,0.f,0.f};
    #pragma unroll 4
    for (int k = 0; k < 64; k += 4){
      float4 hv = *reinterpret_cast<const float4*>(hr + k);
      float hk[4] = {hv.x, hv.y, hv.z, hv.w};
      #pragma unroll
      for (int kk = 0; kk < 4; kk++){
        #pragma unroll
        for (int r = 0; r < 4; r++)
          acc[r] += hk[kk] * sW[(k+kk)*256 + r*64 + lane];
      }
    }
    #pragma unroll
    for (int r = 0; r < 4; r++) h1[(size_t)n*256 + r*64 + lane] = acc[r];
    #pragma unroll
    for (int r = 0; r < 4; r++){
      float vs = wred_sum(acc[r] * avs[r]);
      float vd = wred_sum(acc[r] * avd[r]);
      if (lane == 0){ as1[n*4 + r] = vs; ad1[n*4 + r] = vd; }
    }
  }
}

// ---------------- conv1 aggregate: edge-parallel alpha + vectorized gather ----------------
// 1 wave/node. Lane L: head hL=L>>4, channels c4=(L&15)*4. Online softmax across 64-edge chunks.
__global__ __launch_bounds__(64) void k_gat1(const int* __restrict__ off, const int* __restrict__ srcs,
    const float* __restrict__ as1, const float* __restrict__ ad1,
    const float* __restrict__ h1, const float* __restrict__ b1,
    float* __restrict__ g1, int nN){
  int n = blockIdx.x;
  int L = threadIdx.x;
  int hL = L >> 4, c4 = (L & 15)*4;
  __shared__ int   s_src[64];
  __shared__ float s_p[64][4];
  float ad[4];
  { float4 a = *reinterpret_cast<const float4*>(ad1 + (size_t)n*4);
    ad[0]=a.x; ad[1]=a.y; ad[2]=a.z; ad[3]=a.w; }
  int s0 = off[n], s1 = off[n+1];
  float m[4] = {-1e30f,-1e30f,-1e30f,-1e30f};
  float den[4] = {0.f,0.f,0.f,0.f};
  float4 acc = make_float4(0.f,0.f,0.f,0.f);
  for (int base = s0; base < s1; base += 64){
    int e = base + L;
    int cl = min(64, s1 - base);
    bool valid = (e < s1);
    int sv = 0; float v[4];
    if (valid){
      sv = srcs[e];
      float4 a = *reinterpret_cast<const float4*>(as1 + (size_t)sv*4);
      float av[4] = {a.x,a.y,a.z,a.w};
      #pragma unroll
      for (int h = 0; h < 4; h++){ float tt = av[h] + ad[h]; v[h] = (tt>0.f)?tt:0.2f*tt; }
    } else {
      #pragma unroll
      for (int h = 0; h < 4; h++) v[h] = -1e30f;
    }
    float sc[4];
    #pragma unroll
    for (int h = 0; h < 4; h++){
      float cm = wred_max(v[h]);
      float mn = fmaxf(m[h], cm);
      sc[h] = __expf(m[h] - mn);
      m[h] = mn;
      float p = valid ? __expf(v[h] - mn) : 0.f;
      den[h] = den[h]*sc[h] + wred_sum(p);
      if (valid) s_p[L][h] = p;
    }
    { float s4 = sc[hL]; acc.x*=s4; acc.y*=s4; acc.z*=s4; acc.w*=s4; }
    if (valid) s_src[L] = sv;
    __syncthreads();
    #pragma unroll 4
    for (int e2 = 0; e2 < cl; e2++){
      int sr = s_src[e2];
      float pp = s_p[e2][hL];
      float4 hv = *reinterpret_cast<const float4*>(h1 + (size_t)sr*256 + hL*64 + c4);
      acc.x += pp*hv.x; acc.y += pp*hv.y; acc.z += pp*hv.z; acc.w += pp*hv.w;
    }
    __syncthreads();
  }
  float dl = den[hL] + 1e-16f;
  float4 bb = *reinterpret_cast<const float4*>(b1 + hL*64 + c4);
  float o[4] = {acc.x/dl+bb.x, acc.y/dl+bb.y, acc.z/dl+bb.z, acc.w/dl+bb.w};
  #pragma unroll
  for (int j = 0; j < 4; j++) o[j] = (o[j] > 0.f) ? o[j] : expm1f(o[j]);   // ELU
  *reinterpret_cast<float4*>(g1 + (size_t)n*256 + hL*64 + c4) = make_float4(o[0],o[1],o[2],o[3]);
}

// ---------------- lin2: h2 = g1 @ W2 ; alpha2_s/d ----------------
__global__ __launch_bounds__(256) void k_lin2(const float* __restrict__ g1,
    const float* __restrict__ W2, const float* __restrict__ a2s, const float* __restrict__ a2d,
    float* __restrict__ h2, float* __restrict__ as2, float* __restrict__ ad2, int nN){
  __shared__ float sW[256*64];   // 64 KB
  int t = threadIdx.x, lane = t & 63, w = t >> 6;
  for (int i = t; i < 256*64; i += 256) sW[i] = W2[i];
  __syncthreads();
  float a2sv = a2s[lane], a2dv = a2d[lane];
  for (int nb = 0; nb < 8; nb++){
    int n = blockIdx.x*32 + nb*4 + w;
    if (n >= nN) continue;
    const float* gr = g1 + (size_t)n*256;
    float acc = 0.f;
    #pragma unroll 4
    for (int k = 0; k < 256; k += 4){
      float4 gv = *reinterpret_cast<const float4*>(gr + k);
      acc += gv.x * sW[(k+0)*64 + lane];
      acc += gv.y * sW[(k+1)*64 + lane];
      acc += gv.z * sW[(k+2)*64 + lane];
      acc += gv.w * sW[(k+3)*64 + lane];
    }
    h2[(size_t)n*64 + lane] = acc;
    float vs = wred_sum(acc * a2sv);
    float vd = wred_sum(acc * a2dv);
    if (lane == 0){ as2[n] = vs; ad2[n] = vd; }
  }
}

// ---------------- conv2 aggregate: edge-parallel alpha, 4-edge-group gather, fused pooling ----------------
// Lane L: edge-group g=L>>4 (phase B), channels c4=(L&15)*4. Partial accs folded by shfl_xor(16,32).
__global__ __launch_bounds__(64) void k_gat2(const int* __restrict__ off, const int* __restrict__ srcs,
    const float* __restrict__ as2, const float* __restrict__ ad2,
    const float* __restrict__ h2, const float* __restrict__ b2,
    const int* __restrict__ batch, float* __restrict__ pool, int* __restrict__ cnt, int nN){
  int n = blockIdx.x;
  int L = threadIdx.x;
  int g = L >> 4, c4 = (L & 15)*4;
  __shared__ int   s_src[64];
  __shared__ float s_p[64];
  float ad = ad2[n];
  int s0 = off[n], s1 = off[n+1];
  float m = -1e30f, den = 0.f;
  float4 acc = make_float4(0.f,0.f,0.f,0.f);
  for (int base = s0; base < s1; base += 64){
    int e = base + L;
    int cl = min(64, s1 - base);
    bool valid = (e < s1);
    int sv = 0; float v = -1e30f;
    if (valid){
      sv = srcs[e];
      float tt = as2[sv] + ad;
      v = (tt>0.f)?tt:0.2f*tt;
    }
    float cm = wred_max(v);
    float mn = fmaxf(m, cm);
    float sc = __expf(m - mn);
    m = mn;
    float p = valid ? __expf(v - mn) : 0.f;
    den = den*sc + wred_sum(p);
    acc.x*=sc; acc.y*=sc; acc.z*=sc; acc.w*=sc;
    if (valid){ s_src[L] = sv; s_p[L] = p; }
    __syncthreads();
    for (int e2 = g; e2 < cl; e2 += 4){
      int sr = s_src[e2];
      float pp = s_p[e2];
      float4 hv = *reinterpret_cast<const float4*>(h2 + (size_t)sr*64 + c4);
      acc.x += pp*hv.x; acc.y += pp*hv.y; acc.z += pp*hv.z; acc.w += pp*hv.w;
    }
    __syncthreads();
  }
  // fold 4 edge-groups (lanes differing in bits 4,5)
  #pragma unroll
  for (int s = 16; s <= 32; s <<= 1){
    acc.x += __shfl_xor(acc.x, s, 64);
    acc.y += __shfl_xor(acc.y, s, 64);
    acc.z += __shfl_xor(acc.z, s, 64);
    acc.w += __shfl_xor(acc.w, s, 64);
  }
  float dl = den + 1e-16f;
  int bb = batch[n];
  if (L < 16){
    float4 b4 = *reinterpret_cast<const float4*>(b2 + c4);
    atomicAdd(&pool[bb*64 + c4+0], acc.x/dl + b4.x);
    atomicAdd(&pool[bb*64 + c4+1], acc.y/dl + b4.y);
    atomicAdd(&pool[bb*64 + c4+2], acc.z/dl + b4.z);
    atomicAdd(&pool[bb*64 + c4+3], acc.w/dl + b4.w);
  }
  if (L == 0) atomicAdd(&cnt[bb], 1);
}

// ---------------- final: out[b] = (pool[b]/max(cnt,1)) @ Wl + bl ----------------
__global__ __launch_bounds__(64) void k_final(const float* __restrict__ pool, const int* __restrict__ cnt,
    const float* __restrict__ Wl, const float* __restrict__ bl, float* __restrict__ out, int B){
  int b = blockIdx.x, c = threadIdx.x;
  float cn = fmaxf((float)cnt[b], 1.0f);
  float g = pool[b*64 + c] / cn;
  float v = wred_sum(g * Wl[c]);
  if (c == 0) out[b] = v + bl[0];
}

extern "C" void kernel_launch(void* const* d_in, const int* in_sizes, int n_in,
                              void* d_out, int out_size, void* d_ws, size_t ws_size,
                              hipStream_t stream){
  const float* x    = (const float*)d_in[0];
  const int*   ntyp = (const int*)  d_in[1];
  const int*   ei   = (const int*)  d_in[2];
  const int*   batch= (const int*)  d_in[3];
  const float* Wt = (const float*)d_in[4];
  const float* bt = (const float*)d_in[5];
  const float* Wv = (const float*)d_in[6];
  const float* bv = (const float*)d_in[7];
  const float* Wa = (const float*)d_in[8];
  const float* ba = (const float*)d_in[9];
  const float* W1 = (const float*)d_in[10];
  const float* a1s= (const float*)d_in[11];
  const float* a1d= (const float*)d_in[12];
  const float* b1 = (const float*)d_in[13];
  const float* W2 = (const float*)d_in[14];
  const float* a2s= (const float*)d_in[15];
  const float* a2d= (const float*)d_in[16];
  const float* b2 = (const float*)d_in[17];
  const float* Wl = (const float*)d_in[18];
  const float* bl = (const float*)d_in[19];

  const int N = in_sizes[1];
  const int E = in_sizes[2] / 2;
  const int B = out_size;
  const int nblk = (N + 255)/256;

  char* ws = (char*)d_ws;
  size_t o = 0;
  auto alloc = [&](size_t bytes) -> void* {
    void* p = ws + o;
    o = (o + bytes + 255) & ~(size_t)255;
    return p;
  };
  int*   csr_off = (int*)  alloc((size_t)(N+1)*4);
  int*   pos     = (int*)  alloc((size_t)N*4);
  int*   csr_src = (int*)  alloc((size_t)(E+N)*4);
  float* as1     = (float*)alloc((size_t)N*4*4);
  float* ad1     = (float*)alloc((size_t)N*4*4);
  float* h0      = (float*)alloc((size_t)N*64*4);
  float* h1      = (float*)alloc((size_t)N*256*4);
  float* g1      = (float*)alloc((size_t)N*256*4);
  float* pool    = (float*)alloc((size_t)B*64*4);
  int*   cnt     = (int*)  alloc((size_t)B*4);
  int*   bcnt    = (int*)  alloc((size_t)nblk*3*4);
  int*   boff    = (int*)  alloc((size_t)nblk*3*4);
  int*   toff    = (int*)  alloc(3*4);
  int*   tcnt    = (int*)  alloc(3*4);
  int*   order   = (int*)  alloc((size_t)N*4);
  // aliases (dead-after relationships): h2 reuses h0; alpha2 reuses alpha1
  float* h2  = h0;        // h0 dead after k_lin1
  float* as2 = as1;       // as1/ad1 dead after k_gat1
  float* ad2 = ad1;

  hipMemsetAsync(pool, 0, (size_t)B*64*4, stream);
  hipMemsetAsync(cnt,  0, (size_t)B*4,    stream);

  // type buckets (ballot-based, no global atomics)
  k_bcount  <<<nblk, 256, 0, stream>>>(ntyp, N, nblk, bcnt);
  k_bscan   <<<1, 1024, 0, stream>>>(bcnt, nblk, N, boff, toff, tcnt);
  k_bscatter<<<nblk, 256, 0, stream>>>(ntyp, N, nblk, boff, order);

  // CSR build
  k_deg_init <<<(N + 255)/256, 256, 0, stream>>>(pos, N);
  k_deg_edges<<<(E + 255)/256, 256, 0, stream>>>(ei, E, pos);
  k_scan     <<<1, 1024, 0, stream>>>(pos, csr_off, N);
  k_pos_copy <<<(N + 255)/256, 256, 0, stream>>>(csr_off, pos, N);
  k_scatter  <<<(E + N + 255)/256, 256, 0, stream>>>(ei, E, N, pos, csr_src);

  // projection (bucketed tiled GEMM)
  {
    dim3 g((N + 63)/64, 3);
    k_projgemm<<<g, 256, 0, stream>>>(x, order, toff, tcnt, Wt, bt, Wv, bv, Wa, ba, h0);
  }

  k_lin1<<<(N + 31)/32, 256, 0, stream>>>(h0, W1, a1s, a1d, h1, as1, ad1, N);
  k_gat1<<<N, 64, 0, stream>>>(csr_off, csr_src, as1, ad1, h1, b1, g1, N);
  k_lin2<<<(N + 31)/32, 256, 0, stream>>>(g1, W2, a2s, a2d, h2, as2, ad2, N);
  k_gat2<<<N, 64, 0, stream>>>(csr_off, csr_src, as2, ad2, h2, b2, batch, pool, cnt, N);
  k_final<<<B, 64, 0, stream>>>(pool, cnt, Wl, bl, (float*)d_out, B);
}

// Round 7
// 654.582 us; speedup vs baseline: 2.1986x; 1.2196x over previous
//
#include <hip/hip_runtime.h>
#include <cstdint>
#include <cstddef>

#define TEXTD 768
#define VISD  512
#define AUDD  128

__device__ __forceinline__ float wred_sum(float v){
  #pragma unroll
  for (int m = 32; m >= 1; m >>= 1) v += __shfl_xor(v, m, 64);
  return v;
}
__device__ __forceinline__ float wred_max(float v){
  #pragma unroll
  for (int m = 32; m >= 1; m >>= 1) v = fmaxf(v, __shfl_xor(v, m, 64));
  return v;
}

// ---------------- type bucketing (hierarchical ballot sort; NO global atomics) ----------------
__global__ __launch_bounds__(256) void k_bcount(const int* __restrict__ ntype, int nN, int nblk,
                                                int* __restrict__ bcnt){
  int b = blockIdx.x;
  int i = b*256 + threadIdx.x;
  int lane = threadIdx.x & 63, w = threadIdx.x >> 6;
  int ty = (i < nN) ? ntype[i] : -1;
  __shared__ int wc[4][3];
  #pragma unroll
  for (int t = 0; t < 3; t++){
    unsigned long long m = __ballot(ty == t);
    if (lane == 0) wc[w][t] = __popcll(m);
  }
  __syncthreads();
  if (threadIdx.x < 3){
    int t = threadIdx.x;
    bcnt[t*nblk + b] = wc[0][t] + wc[1][t] + wc[2][t] + wc[3][t];
  }
}
__global__ __launch_bounds__(1024) void k_bscan(const int* __restrict__ bcnt, int nblk, int nN,
                                                int* __restrict__ boff, int* __restrict__ toff,
                                                int* __restrict__ tcnt){
  __shared__ int s[2048];          // supports nblk*3 <= 2048
  int n3 = nblk*3;
  int t = threadIdx.x;
  for (int i = t; i < n3; i += 1024) s[i] = bcnt[i];
  __syncthreads();
  if (t == 0){
    int run = 0;
    for (int i = 0; i < n3; i++){ int v = s[i]; s[i] = run; run += v; }
  }
  __syncthreads();
  for (int i = t; i < n3; i += 1024) boff[i] = s[i];
  if (t == 0){
    toff[0] = 0;         toff[1] = s[nblk];           toff[2] = s[2*nblk];
    tcnt[0] = s[nblk];   tcnt[1] = s[2*nblk]-s[nblk]; tcnt[2] = nN - s[2*nblk];
  }
}
__global__ __launch_bounds__(256) void k_bscatter(const int* __restrict__ ntype, int nN, int nblk,
                                                  const int* __restrict__ boff, int* __restrict__ order){
  int b = blockIdx.x;
  int i = b*256 + threadIdx.x;
  int lane = threadIdx.x & 63, w = threadIdx.x >> 6;
  int ty = (i < nN) ? ntype[i] : -1;
  __shared__ int wc[4][3];
  __shared__ int woff[4][3];
  unsigned long long masks[3];
  #pragma unroll
  for (int t = 0; t < 3; t++){
    masks[t] = __ballot(ty == t);
    if (lane == 0) wc[w][t] = __popcll(masks[t]);
  }
  __syncthreads();
  if (threadIdx.x < 3){
    int t = threadIdx.x, run = 0;
    #pragma unroll
    for (int ww = 0; ww < 4; ww++){ woff[ww][t] = run; run += wc[ww][t]; }
  }
  __syncthreads();
  if (ty >= 0){
    int r = __popcll(masks[ty] & ((1ULL << lane) - 1ULL));
    int pos = boff[ty*nblk + b] + woff[w][ty] + r;
    order[pos] = i;
  }
}

// ---------------- projection as bucketed tiled GEMM ----------------
__global__ __launch_bounds__(256) void k_projgemm(const float* __restrict__ x,
    const int* __restrict__ order, const int* __restrict__ toff, const int* __restrict__ tcnt,
    const float* __restrict__ Wt, const float* __restrict__ bt,
    const float* __restrict__ Wv, const float* __restrict__ bv,
    const float* __restrict__ Wa, const float* __restrict__ ba,
    float* __restrict__ h0){
  int ty = blockIdx.y;
  int cnt = tcnt[ty];
  int tile = blockIdx.x;
  if (tile*64 >= cnt) return;
  const float* W; const float* bias; int dim;
  if (ty == 0)      { W = Wt; bias = bt; dim = TEXTD; }
  else if (ty == 1) { W = Wv; bias = bv; dim = VISD; }
  else              { W = Wa; bias = ba; dim = AUDD; }
  int off = toff[ty];

  __shared__ float xsT[64][68];
  __shared__ float ws [64][68];
  __shared__ int   nid[64];

  int t = threadIdx.x;
  if (t < 64){
    int idx = tile*64 + t;
    nid[t] = (idx < cnt) ? order[off + idx] : -1;
  }
  __syncthreads();

  int node_l = t & 63;
  int ndl = nid[node_l];
  const float* xrow = x + (size_t)(ndl < 0 ? 0 : ndl) * TEXTD;
  int wrow = t >> 2, wu = t & 3;
  int wvq  = t >> 6;
  int n0 = (t & 15)*4, c0 = (t >> 4)*4;
  float acc[4][4] = {};

  for (int k0 = 0; k0 < dim; k0 += 64){
    __syncthreads();
    #pragma unroll
    for (int j = 0; j < 4; j++){
      int f4 = wvq*4 + j;
      float4 v = *reinterpret_cast<const float4*>(xrow + k0 + f4*4);
      xsT[f4*4+0][node_l] = v.x;
      xsT[f4*4+1][node_l] = v.y;
      xsT[f4*4+2][node_l] = v.z;
      xsT[f4*4+3][node_l] = v.w;
    }
    #pragma unroll
    for (int j = 0; j < 4; j++){
      int f4 = j*4 + wu;
      float4 v = *reinterpret_cast<const float4*>(W + (size_t)(k0 + wrow)*64 + f4*4);
      *reinterpret_cast<float4*>(&ws[wrow][f4*4]) = v;
    }
    __syncthreads();
    #pragma unroll 8
    for (int kk = 0; kk < 64; kk++){
      float4 xv = *reinterpret_cast<const float4*>(&xsT[kk][n0]);
      float4 wv = *reinterpret_cast<const float4*>(&ws[kk][c0]);
      float xa[4] = {xv.x, xv.y, xv.z, xv.w};
      float wb[4] = {wv.x, wv.y, wv.z, wv.w};
      #pragma unroll
      for (int i = 0; i < 4; i++)
        #pragma unroll
        for (int j = 0; j < 4; j++)
          acc[i][j] += xa[i] * wb[j];
    }
  }

  float4 b4 = *reinterpret_cast<const float4*>(bias + c0);
  float bb[4] = {b4.x, b4.y, b4.z, b4.w};
  #pragma unroll
  for (int i = 0; i < 4; i++){
    int nd = nid[n0 + i];
    if (nd >= 0){
      float4 o4 = make_float4(acc[i][0]+bb[0], acc[i][1]+bb[1], acc[i][2]+bb[2], acc[i][3]+bb[3]);
      *reinterpret_cast<float4*>(h0 + (size_t)nd*64 + c0) = o4;
    }
  }
}

// ---------------- CSR build ----------------
__global__ void k_deg_init(int* __restrict__ deg, int nN){
  int i = blockIdx.x*blockDim.x + threadIdx.x;
  if (i < nN) deg[i] = 1;                    // self-loop
}
__global__ void k_deg_edges(const int* __restrict__ ei, int E, int* __restrict__ deg){
  int i = blockIdx.x*blockDim.x + threadIdx.x;
  if (i < E) atomicAdd(&deg[ei[E + i]], 1);  // dst row
}
__global__ __launch_bounds__(1024) void k_scan(const int* __restrict__ deg, int* __restrict__ off, int n){
  __shared__ int wsum[16];
  __shared__ int carry_s;
  int t = threadIdx.x, lane = t & 63, w = t >> 6;
  if (t == 0) carry_s = 0;
  __syncthreads();
  for (int base = 0; base < n; base += 1024){
    int i = base + t;
    int v = (i < n) ? deg[i] : 0;
    int orig = v;
    #pragma unroll
    for (int o = 1; o < 64; o <<= 1){ int u = __shfl_up(v, o, 64); if (lane >= o) v += u; }
    if (lane == 63) wsum[w] = v;
    __syncthreads();
    if (t < 16){
      int xv = wsum[t];
      #pragma unroll
      for (int o = 1; o < 16; o <<= 1){ int u = __shfl_up(xv, o, 16); if (t >= o) xv += u; }
      wsum[t] = xv;
    }
    __syncthreads();
    int wbase = (w == 0) ? 0 : wsum[w-1];
    int incl = v + wbase;
    int carry = carry_s;
    if (i < n) off[i] = carry + incl - orig;
    __syncthreads();
    if (t == 0) carry_s = carry + wsum[15];
    __syncthreads();
  }
  if (threadIdx.x == 0) off[n] = carry_s;
}
__global__ void k_pos_copy(const int* __restrict__ off, int* __restrict__ pos, int nN){
  int i = blockIdx.x*blockDim.x + threadIdx.x;
  if (i < nN) pos[i] = off[i];
}
__global__ void k_scatter(const int* __restrict__ ei, int E, int nN,
                          int* __restrict__ pos, int* __restrict__ csr_src){
  int i = blockIdx.x*blockDim.x + threadIdx.x;
  int total = E + nN;
  if (i >= total) return;
  int s, d;
  if (i < E){ s = ei[i]; d = ei[E + i]; } else { s = i - E; d = s; }
  int p = atomicAdd(&pos[d], 1);
  csr_src[p] = s;
}

// ---------------- lin1: h1 = h0 @ W1 ; alpha1_s/d per head (wave reduce) ----------------
__global__ __launch_bounds__(256) void k_lin1(const float* __restrict__ h0,
    const float* __restrict__ W1, const float* __restrict__ a1s, const float* __restrict__ a1d,
    float* __restrict__ h1, float* __restrict__ as1, float* __restrict__ ad1, int nN){
  __shared__ float sW[64*256];   // 64 KB
  int t = threadIdx.x, lane = t & 63, w = t >> 6;
  for (int i = t; i < 64*256; i += 256) sW[i] = W1[i];
  __syncthreads();
  float avs[4], avd[4];
  #pragma unroll
  for (int r = 0; r < 4; r++){ avs[r] = a1s[r*64 + lane]; avd[r] = a1d[r*64 + lane]; }
  for (int nb = 0; nb < 8; nb++){
    int n = blockIdx.x*32 + nb*4 + w;      // one wave per node
    if (n >= nN) continue;
    const float* hr = h0 + (size_t)n*64;
    float acc[4] = {0.f,0.f,0.f,0.f};
    #pragma unroll 4
    for (int k = 0; k < 64; k += 4){
      float4 hv = *reinterpret_cast<const float4*>(hr + k);
      float hk[4] = {hv.x, hv.y, hv.z, hv.w};
      #pragma unroll
      for (int kk = 0; kk < 4; kk++){
        #pragma unroll
        for (int r = 0; r < 4; r++)
          acc[r] += hk[kk] * sW[(k+kk)*256 + r*64 + lane];
      }
    }
    #pragma unroll
    for (int r = 0; r < 4; r++) h1[(size_t)n*256 + r*64 + lane] = acc[r];
    #pragma unroll
    for (int r = 0; r < 4; r++){
      float vs = wred_sum(acc[r] * avs[r]);
      float vd = wred_sum(acc[r] * avd[r]);
      if (lane == 0){ as1[n*4 + r] = vs; ad1[n*4 + r] = vd; }
    }
  }
}

// ---------------- conv1 aggregate: edge-parallel alpha + vectorized gather ----------------
__global__ __launch_bounds__(64) void k_gat1(const int* __restrict__ off, const int* __restrict__ srcs,
    const float* __restrict__ as1, const float* __restrict__ ad1,
    const float* __restrict__ h1, const float* __restrict__ b1,
    float* __restrict__ g1, int nN){
  int n = blockIdx.x;
  int L = threadIdx.x;
  int hL = L >> 4, c4 = (L & 15)*4;
  __shared__ int   s_src[64];
  __shared__ float s_p[64][4];
  float ad[4];
  { float4 a = *reinterpret_cast<const float4*>(ad1 + (size_t)n*4);
    ad[0]=a.x; ad[1]=a.y; ad[2]=a.z; ad[3]=a.w; }
  int s0 = off[n], s1 = off[n+1];
  float m[4] = {-1e30f,-1e30f,-1e30f,-1e30f};
  float den[4] = {0.f,0.f,0.f,0.f};
  float4 acc = make_float4(0.f,0.f,0.f,0.f);
  for (int base = s0; base < s1; base += 64){
    int e = base + L;
    int cl = min(64, s1 - base);
    bool valid = (e < s1);
    int sv = 0; float v[4];
    if (valid){
      sv = srcs[e];
      float4 a = *reinterpret_cast<const float4*>(as1 + (size_t)sv*4);
      float av[4] = {a.x,a.y,a.z,a.w};
      #pragma unroll
      for (int h = 0; h < 4; h++){ float tt = av[h] + ad[h]; v[h] = (tt>0.f)?tt:0.2f*tt; }
    } else {
      #pragma unroll
      for (int h = 0; h < 4; h++) v[h] = -1e30f;
    }
    float sc[4];
    #pragma unroll
    for (int h = 0; h < 4; h++){
      float cm = wred_max(v[h]);
      float mn = fmaxf(m[h], cm);
      sc[h] = __expf(m[h] - mn);
      m[h] = mn;
      float p = valid ? __expf(v[h] - mn) : 0.f;
      den[h] = den[h]*sc[h] + wred_sum(p);
      if (valid) s_p[L][h] = p;
    }
    { float s4 = sc[hL]; acc.x*=s4; acc.y*=s4; acc.z*=s4; acc.w*=s4; }
    if (valid) s_src[L] = sv;
    __syncthreads();
    #pragma unroll 4
    for (int e2 = 0; e2 < cl; e2++){
      int sr = s_src[e2];
      float pp = s_p[e2][hL];
      float4 hv = *reinterpret_cast<const float4*>(h1 + (size_t)sr*256 + hL*64 + c4);
      acc.x += pp*hv.x; acc.y += pp*hv.y; acc.z += pp*hv.z; acc.w += pp*hv.w;
    }
    __syncthreads();
  }
  float dl = den[hL] + 1e-16f;
  float4 bb = *reinterpret_cast<const float4*>(b1 + hL*64 + c4);
  float o[4] = {acc.x/dl+bb.x, acc.y/dl+bb.y, acc.z/dl+bb.z, acc.w/dl+bb.w};
  #pragma unroll
  for (int j = 0; j < 4; j++) o[j] = (o[j] > 0.f) ? o[j] : expm1f(o[j]);   // ELU
  *reinterpret_cast<float4*>(g1 + (size_t)n*256 + hL*64 + c4) = make_float4(o[0],o[1],o[2],o[3]);
}

// ---------------- lin2: h2 = g1 @ W2 ; alpha2_s/d ----------------
__global__ __launch_bounds__(256) void k_lin2(const float* __restrict__ g1,
    const float* __restrict__ W2, const float* __restrict__ a2s, const float* __restrict__ a2d,
    float* __restrict__ h2, float* __restrict__ as2, float* __restrict__ ad2, int nN){
  __shared__ float sW[256*64];   // 64 KB
  int t = threadIdx.x, lane = t & 63, w = t >> 6;
  for (int i = t; i < 256*64; i += 256) sW[i] = W2[i];
  __syncthreads();
  float a2sv = a2s[lane], a2dv = a2d[lane];
  for (int nb = 0; nb < 8; nb++){
    int n = blockIdx.x*32 + nb*4 + w;
    if (n >= nN) continue;
    const float* gr = g1 + (size_t)n*256;
    float acc = 0.f;
    #pragma unroll 4
    for (int k = 0; k < 256; k += 4){
      float4 gv = *reinterpret_cast<const float4*>(gr + k);
      acc += gv.x * sW[(k+0)*64 + lane];
      acc += gv.y * sW[(k+1)*64 + lane];
      acc += gv.z * sW[(k+2)*64 + lane];
      acc += gv.w * sW[(k+3)*64 + lane];
    }
    h2[(size_t)n*64 + lane] = acc;
    float vs = wred_sum(acc * a2sv);
    float vd = wred_sum(acc * a2dv);
    if (lane == 0){ as2[n] = vs; ad2[n] = vd; }
  }
}

// ---------------- conv2 aggregate + b2 -> per-node vector g2[n][64] (NO atomics) ----------------
// 4 waves/block, 1 node/wave. Lane L: edge-group g=L>>4, channels c4=(L&15)*4.
// shfl-broadcast with WAVE-UNIFORM trip count + clamped source lane:
// every __shfl executes with all 64 lanes active (ds_bpermute from an
// exec-masked-off lane is UNDEFINED -- this was the R5/R6 correctness bug).
__global__ __launch_bounds__(256) void k_gat2v(const int* __restrict__ off, const int* __restrict__ srcs,
    const float* __restrict__ as2, const float* __restrict__ ad2,
    const float* __restrict__ h2, const float* __restrict__ b2,
    float* __restrict__ g2, int nN){
  int w = threadIdx.x >> 6, L = threadIdx.x & 63;
  int n = blockIdx.x*4 + w;
  if (n >= nN) return;
  int g = L >> 4, c4 = (L & 15)*4;
  float ad = ad2[n];
  int s0 = off[n], s1 = off[n+1];
  float m = -1e30f, den = 0.f;
  float4 acc = make_float4(0.f,0.f,0.f,0.f);
  for (int base = s0; base < s1; base += 64){
    int e = base + L;
    int cl = min(64, s1 - base);
    bool valid = (e < s1);
    int sv = 0; float v = -1e30f;
    if (valid){
      sv = srcs[e];
      float tt = as2[sv] + ad;
      v = (tt>0.f)?tt:0.2f*tt;
    }
    float cm = wred_max(v);
    float mn = fmaxf(m, cm);
    float sc = __expf(m - mn);
    m = mn;
    float p = valid ? __expf(v - mn) : 0.f;
    den = den*sc + wred_sum(p);
    acc.x*=sc; acc.y*=sc; acc.z*=sc; acc.w*=sc;
    int iters = (cl + 3) >> 2;          // wave-uniform trip count
    for (int it = 0; it < iters; ++it){
      int e2   = it*4 + g;
      int esrc = (e2 < cl) ? e2 : (cl - 1);   // clamp -> source lane always < cl (active)
      int   sr = __shfl(sv, esrc, 64);
      float pp = __shfl(p,  esrc, 64);
      if (e2 < cl){
        float4 hv = *reinterpret_cast<const float4*>(h2 + (size_t)sr*64 + c4);
        acc.x += pp*hv.x; acc.y += pp*hv.y; acc.z += pp*hv.z; acc.w += pp*hv.w;
      }
    }
  }
  // fold 4 edge-groups (lanes differing in bits 4,5)
  #pragma unroll
  for (int s = 16; s <= 32; s <<= 1){
    acc.x += __shfl_xor(acc.x, s, 64);
    acc.y += __shfl_xor(acc.y, s, 64);
    acc.z += __shfl_xor(acc.z, s, 64);
    acc.w += __shfl_xor(acc.w, s, 64);
  }
  float dl = den + 1e-16f;
  if (L < 16){
    float4 b4 = *reinterpret_cast<const float4*>(b2 + c4);
    float4 o4 = make_float4(acc.x/dl + b4.x, acc.y/dl + b4.y,
                            acc.z/dl + b4.z, acc.w/dl + b4.w);
    *reinterpret_cast<float4*>(g2 + (size_t)n*64 + c4) = o4;
  }
}

// ---------------- bucket starts from SORTED batch (boundary detect, no atomics) ----------------
__global__ void k_bstart(const int* __restrict__ batch, int nN, int B, int* __restrict__ bstart){
  int i = blockIdx.x*blockDim.x + threadIdx.x;
  if (i < nN){
    int prev = (i == 0) ? -1 : batch[i-1];
    int cur  = batch[i];
    for (int b = prev+1; b <= cur; b++) bstart[b] = i;
  } else if (i == nN){
    int last = batch[nN-1];
    for (int b = last+1; b <= B; b++) bstart[b] = nN;
  }
}

// ---------------- pool: out[b] = mean(g2 rows) @ Wl + bl   (mean BEFORE dot: matches ref order) ----
__global__ __launch_bounds__(64) void k_pool(const float* __restrict__ g2, const int* __restrict__ bstart,
    const float* __restrict__ Wl, const float* __restrict__ bl, float* __restrict__ out, int B){
  int b = blockIdx.x, c = threadIdx.x;
  int r0 = bstart[b], r1 = bstart[b+1];
  float s = 0.f;
  int i = r0;
  for (; i + 4 <= r1; i += 4){
    s += g2[(size_t)(i+0)*64 + c];
    s += g2[(size_t)(i+1)*64 + c];
    s += g2[(size_t)(i+2)*64 + c];
    s += g2[(size_t)(i+3)*64 + c];
  }
  for (; i < r1; i++) s += g2[(size_t)i*64 + c];
  float g = s / fmaxf((float)(r1 - r0), 1.f);
  float v = wred_sum(g * Wl[c]);
  if (c == 0) out[b] = v + bl[0];
}

extern "C" void kernel_launch(void* const* d_in, const int* in_sizes, int n_in,
                              void* d_out, int out_size, void* d_ws, size_t ws_size,
                              hipStream_t stream){
  const float* x    = (const float*)d_in[0];
  const int*   ntyp = (const int*)  d_in[1];
  const int*   ei   = (const int*)  d_in[2];
  const int*   batch= (const int*)  d_in[3];
  const float* Wt = (const float*)d_in[4];
  const float* bt = (const float*)d_in[5];
  const float* Wv = (const float*)d_in[6];
  const float* bv = (const float*)d_in[7];
  const float* Wa = (const float*)d_in[8];
  const float* ba = (const float*)d_in[9];
  const float* W1 = (const float*)d_in[10];
  const float* a1s= (const float*)d_in[11];
  const float* a1d= (const float*)d_in[12];
  const float* b1 = (const float*)d_in[13];
  const float* W2 = (const float*)d_in[14];
  const float* a2s= (const float*)d_in[15];
  const float* a2d= (const float*)d_in[16];
  const float* b2 = (const float*)d_in[17];
  const float* Wl = (const float*)d_in[18];
  const float* bl = (const float*)d_in[19];

  const int N = in_sizes[1];
  const int E = in_sizes[2] / 2;
  const int B = out_size;
  const int nblk = (N + 255)/256;

  char* ws = (char*)d_ws;
  size_t o = 0;
  auto alloc = [&](size_t bytes) -> void* {
    void* p = ws + o;
    o = (o + bytes + 255) & ~(size_t)255;
    return p;
  };
  int*   csr_off = (int*)  alloc((size_t)(N+1)*4);
  int*   pos     = (int*)  alloc((size_t)N*4);
  int*   csr_src = (int*)  alloc((size_t)(E+N)*4);
  float* as1     = (float*)alloc((size_t)N*4*4);
  float* ad1     = (float*)alloc((size_t)N*4*4);
  float* h0      = (float*)alloc((size_t)N*64*4);
  float* h1      = (float*)alloc((size_t)N*256*4);
  float* g1      = (float*)alloc((size_t)N*256*4);
  int*   bstart  = (int*)  alloc((size_t)(B+1)*4);
  int*   bcnt    = (int*)  alloc((size_t)nblk*3*4);
  int*   boff    = (int*)  alloc((size_t)nblk*3*4);
  int*   toff    = (int*)  alloc(3*4);
  int*   tcnt    = (int*)  alloc(3*4);
  int*   order   = (int*)  alloc((size_t)N*4);
  // aliases (dead-after relationships): h2 reuses h0; alpha2 reuses alpha1; g2 reuses h1
  float* h2  = h0;        // h0 dead after k_lin1
  float* as2 = as1;       // as1/ad1 dead after k_gat1
  float* ad2 = ad1;
  float* g2  = h1;        // h1 dead after k_gat1

  // type buckets (ballot-based, no global atomics)
  k_bcount  <<<nblk, 256, 0, stream>>>(ntyp, N, nblk, bcnt);
  k_bscan   <<<1, 1024, 0, stream>>>(bcnt, nblk, N, boff, toff, tcnt);
  k_bscatter<<<nblk, 256, 0, stream>>>(ntyp, N, nblk, boff, order);

  // CSR build
  k_deg_init <<<(N + 255)/256, 256, 0, stream>>>(pos, N);
  k_deg_edges<<<(E + 255)/256, 256, 0, stream>>>(ei, E, pos);
  k_scan     <<<1, 1024, 0, stream>>>(pos, csr_off, N);
  k_pos_copy <<<(N + 255)/256, 256, 0, stream>>>(csr_off, pos, N);
  k_scatter  <<<(E + N + 255)/256, 256, 0, stream>>>(ei, E, N, pos, csr_src);

  // batch bucket starts (sorted batch; no atomics)
  k_bstart<<<(N + 1 + 255)/256, 256, 0, stream>>>(batch, N, B, bstart);

  // projection (bucketed tiled GEMM)
  {
    dim3 g((N + 63)/64, 3);
    k_projgemm<<<g, 256, 0, stream>>>(x, order, toff, tcnt, Wt, bt, Wv, bv, Wa, ba, h0);
  }

  k_lin1<<<(N + 31)/32, 256, 0, stream>>>(h0, W1, a1s, a1d, h1, as1, ad1, N);
  k_gat1<<<N, 64, 0, stream>>>(csr_off, csr_src, as1, ad1, h1, b1, g1, N);
  k_lin2<<<(N + 31)/32, 256, 0, stream>>>(g1, W2, a2s, a2d, h2, as2, ad2, N);
  k_gat2v<<<(N + 3)/4, 256, 0, stream>>>(csr_off, csr_src, as2, ad2, h2, b2, g2, N);
  k_pool<<<B, 64, 0, stream>>>(g2, bstart, Wl, bl, (float*)d_out, B);
}

// Round 8
// 459.120 us; speedup vs baseline: 3.1346x; 1.4257x over previous
//
#include <hip/hip_runtime.h>
#include <cstdint>
#include <cstddef>

#define TEXTD 768
#define VISD  512
#define AUDD  128

__device__ __forceinline__ float wred_sum(float v){
  #pragma unroll
  for (int m = 32; m >= 1; m >>= 1) v += __shfl_xor(v, m, 64);
  return v;
}
__device__ __forceinline__ float wred_max(float v){
  #pragma unroll
  for (int m = 32; m >= 1; m >>= 1) v = fmaxf(v, __shfl_xor(v, m, 64));
  return v;
}

// ---------------- type bucketing (hierarchical ballot sort; NO global atomics) ----------------
__global__ __launch_bounds__(256) void k_bcount(const int* __restrict__ ntype, int nN, int nblk,
                                                int* __restrict__ bcnt){
  int b = blockIdx.x;
  int i = b*256 + threadIdx.x;
  int lane = threadIdx.x & 63, w = threadIdx.x >> 6;
  int ty = (i < nN) ? ntype[i] : -1;
  __shared__ int wc[4][3];
  #pragma unroll
  for (int t = 0; t < 3; t++){
    unsigned long long m = __ballot(ty == t);
    if (lane == 0) wc[w][t] = __popcll(m);
  }
  __syncthreads();
  if (threadIdx.x < 3){
    int t = threadIdx.x;
    bcnt[t*nblk + b] = wc[0][t] + wc[1][t] + wc[2][t] + wc[3][t];
  }
}
__global__ __launch_bounds__(1024) void k_bscan(const int* __restrict__ bcnt, int nblk, int nN,
                                                int* __restrict__ boff, int* __restrict__ toff,
                                                int* __restrict__ tcnt){
  __shared__ int s[2048];          // supports nblk*3 <= 2048
  int n3 = nblk*3;
  int t = threadIdx.x;
  for (int i = t; i < n3; i += 1024) s[i] = bcnt[i];
  __syncthreads();
  if (t == 0){
    int run = 0;
    for (int i = 0; i < n3; i++){ int v = s[i]; s[i] = run; run += v; }
  }
  __syncthreads();
  for (int i = t; i < n3; i += 1024) boff[i] = s[i];
  if (t == 0){
    toff[0] = 0;         toff[1] = s[nblk];           toff[2] = s[2*nblk];
    tcnt[0] = s[nblk];   tcnt[1] = s[2*nblk]-s[nblk]; tcnt[2] = nN - s[2*nblk];
  }
}
__global__ __launch_bounds__(256) void k_bscatter(const int* __restrict__ ntype, int nN, int nblk,
                                                  const int* __restrict__ boff, int* __restrict__ order){
  int b = blockIdx.x;
  int i = b*256 + threadIdx.x;
  int lane = threadIdx.x & 63, w = threadIdx.x >> 6;
  int ty = (i < nN) ? ntype[i] : -1;
  __shared__ int wc[4][3];
  __shared__ int woff[4][3];
  unsigned long long masks[3];
  #pragma unroll
  for (int t = 0; t < 3; t++){
    masks[t] = __ballot(ty == t);
    if (lane == 0) wc[w][t] = __popcll(masks[t]);
  }
  __syncthreads();
  if (threadIdx.x < 3){
    int t = threadIdx.x, run = 0;
    #pragma unroll
    for (int ww = 0; ww < 4; ww++){ woff[ww][t] = run; run += wc[ww][t]; }
  }
  __syncthreads();
  if (ty >= 0){
    int r = __popcll(masks[ty] & ((1ULL << lane) - 1ULL));
    int pos = boff[ty*nblk + b] + woff[w][ty] + r;
    order[pos] = i;
  }
}

// ---------------- projection as bucketed tiled GEMM ----------------
__global__ __launch_bounds__(256) void k_projgemm(const float* __restrict__ x,
    const int* __restrict__ order, const int* __restrict__ toff, const int* __restrict__ tcnt,
    const float* __restrict__ Wt, const float* __restrict__ bt,
    const float* __restrict__ Wv, const float* __restrict__ bv,
    const float* __restrict__ Wa, const float* __restrict__ ba,
    float* __restrict__ h0){
  int ty = blockIdx.y;
  int cnt = tcnt[ty];
  int tile = blockIdx.x;
  if (tile*64 >= cnt) return;
  const float* W; const float* bias; int dim;
  if (ty == 0)      { W = Wt; bias = bt; dim = TEXTD; }
  else if (ty == 1) { W = Wv; bias = bv; dim = VISD; }
  else              { W = Wa; bias = ba; dim = AUDD; }
  int off = toff[ty];

  __shared__ float xsT[64][68];
  __shared__ float ws [64][68];
  __shared__ int   nid[64];

  int t = threadIdx.x;
  if (t < 64){
    int idx = tile*64 + t;
    nid[t] = (idx < cnt) ? order[off + idx] : -1;
  }
  __syncthreads();

  int node_l = t & 63;
  int ndl = nid[node_l];
  const float* xrow = x + (size_t)(ndl < 0 ? 0 : ndl) * TEXTD;
  int wrow = t >> 2, wu = t & 3;
  int wvq  = t >> 6;
  int n0 = (t & 15)*4, c0 = (t >> 4)*4;
  float acc[4][4] = {};

  for (int k0 = 0; k0 < dim; k0 += 64){
    __syncthreads();
    #pragma unroll
    for (int j = 0; j < 4; j++){
      int f4 = wvq*4 + j;
      float4 v = *reinterpret_cast<const float4*>(xrow + k0 + f4*4);
      xsT[f4*4+0][node_l] = v.x;
      xsT[f4*4+1][node_l] = v.y;
      xsT[f4*4+2][node_l] = v.z;
      xsT[f4*4+3][node_l] = v.w;
    }
    #pragma unroll
    for (int j = 0; j < 4; j++){
      int f4 = j*4 + wu;
      float4 v = *reinterpret_cast<const float4*>(W + (size_t)(k0 + wrow)*64 + f4*4);
      *reinterpret_cast<float4*>(&ws[wrow][f4*4]) = v;
    }
    __syncthreads();
    #pragma unroll 8
    for (int kk = 0; kk < 64; kk++){
      float4 xv = *reinterpret_cast<const float4*>(&xsT[kk][n0]);
      float4 wv = *reinterpret_cast<const float4*>(&ws[kk][c0]);
      float xa[4] = {xv.x, xv.y, xv.z, xv.w};
      float wb[4] = {wv.x, wv.y, wv.z, wv.w};
      #pragma unroll
      for (int i = 0; i < 4; i++)
        #pragma unroll
        for (int j = 0; j < 4; j++)
          acc[i][j] += xa[i] * wb[j];
    }
  }

  float4 b4 = *reinterpret_cast<const float4*>(bias + c0);
  float bb[4] = {b4.x, b4.y, b4.z, b4.w};
  #pragma unroll
  for (int i = 0; i < 4; i++){
    int nd = nid[n0 + i];
    if (nd >= 0){
      float4 o4 = make_float4(acc[i][0]+bb[0], acc[i][1]+bb[1], acc[i][2]+bb[2], acc[i][3]+bb[3]);
      *reinterpret_cast<float4*>(h0 + (size_t)nd*64 + c0) = o4;
    }
  }
}

// ---------------- CSR build ----------------
__global__ void k_deg_init(int* __restrict__ deg, int nN){
  int i = blockIdx.x*blockDim.x + threadIdx.x;
  if (i < nN) deg[i] = 1;                    // self-loop
}
__global__ void k_deg_edges(const int* __restrict__ ei, int E, int* __restrict__ deg){
  int i = blockIdx.x*blockDim.x + threadIdx.x;
  if (i < E) atomicAdd(&deg[ei[E + i]], 1);  // dst row
}
__global__ __launch_bounds__(1024) void k_scan(const int* __restrict__ deg, int* __restrict__ off, int n){
  __shared__ int wsum[16];
  __shared__ int carry_s;
  int t = threadIdx.x, lane = t & 63, w = t >> 6;
  if (t == 0) carry_s = 0;
  __syncthreads();
  for (int base = 0; base < n; base += 1024){
    int i = base + t;
    int v = (i < n) ? deg[i] : 0;
    int orig = v;
    #pragma unroll
    for (int o = 1; o < 64; o <<= 1){ int u = __shfl_up(v, o, 64); if (lane >= o) v += u; }
    if (lane == 63) wsum[w] = v;
    __syncthreads();
    if (t < 16){
      int xv = wsum[t];
      #pragma unroll
      for (int o = 1; o < 16; o <<= 1){ int u = __shfl_up(xv, o, 16); if (t >= o) xv += u; }
      wsum[t] = xv;
    }
    __syncthreads();
    int wbase = (w == 0) ? 0 : wsum[w-1];
    int incl = v + wbase;
    int carry = carry_s;
    if (i < n) off[i] = carry + incl - orig;
    __syncthreads();
    if (t == 0) carry_s = carry + wsum[15];
    __syncthreads();
  }
  if (threadIdx.x == 0) off[n] = carry_s;
}
__global__ void k_pos_copy(const int* __restrict__ off, int* __restrict__ pos, int nN){
  int i = blockIdx.x*blockDim.x + threadIdx.x;
  if (i < nN) pos[i] = off[i];
}
__global__ void k_scatter(const int* __restrict__ ei, int E, int nN,
                          int* __restrict__ pos, int* __restrict__ csr_src){
  int i = blockIdx.x*blockDim.x + threadIdx.x;
  int total = E + nN;
  if (i >= total) return;
  int s, d;
  if (i < E){ s = ei[i]; d = ei[E + i]; } else { s = i - E; d = s; }
  int p = atomicAdd(&pos[d], 1);
  csr_src[p] = s;
}

// ---------------- lin1 as tiled GEMM: h1[n][q*64+c] = h0[n] @ W1[:,q*64+c]; fused alpha1 ------
// grid (ceil(N/64), 4=head). 64 nodes x 64 chans/block, K=64. 4x4 reg tile/thread.
__global__ __launch_bounds__(256) void k_lin1t(const float* __restrict__ h0,
    const float* __restrict__ W1, const float* __restrict__ a1s, const float* __restrict__ a1d,
    float* __restrict__ h1, float* __restrict__ as1, float* __restrict__ ad1, int nN){
  int tile = blockIdx.x, q = blockIdx.y;
  int base = tile*64;
  __shared__ float xsT[64][68];     // [k][node]
  __shared__ float ws [64][68];     // [k][chan]
  __shared__ float sPart[16][64];   // [chan-group][node]
  __shared__ float dPart[16][64];

  int t = threadIdx.x;
  int row = t >> 2, fq = t & 3;
  {                                  // h0 tile -> xsT (coalesced; transposed store)
    int nd = base + row; if (nd >= nN) nd = nN - 1;
    const float* hr = h0 + (size_t)nd*64;
    #pragma unroll
    for (int j = 0; j < 4; j++){
      int f4 = j*4 + fq;
      float4 v = *reinterpret_cast<const float4*>(hr + f4*4);
      xsT[f4*4+0][row] = v.x; xsT[f4*4+1][row] = v.y;
      xsT[f4*4+2][row] = v.z; xsT[f4*4+3][row] = v.w;
    }
  }
  #pragma unroll
  for (int j = 0; j < 4; j++){       // W1 quadrant q -> ws
    int f4 = j*4 + fq;
    float4 v = *reinterpret_cast<const float4*>(W1 + (size_t)row*256 + q*64 + f4*4);
    *reinterpret_cast<float4*>(&ws[row][f4*4]) = v;
  }
  __syncthreads();

  int n0 = (t & 15)*4, c0 = (t >> 4)*4, qg = t >> 4;
  float acc[4][4] = {};
  #pragma unroll 8
  for (int k = 0; k < 64; k++){
    float4 xv = *reinterpret_cast<const float4*>(&xsT[k][n0]);
    float4 wv = *reinterpret_cast<const float4*>(&ws[k][c0]);
    float xa[4] = {xv.x, xv.y, xv.z, xv.w};
    float wb[4] = {wv.x, wv.y, wv.z, wv.w};
    #pragma unroll
    for (int i = 0; i < 4; i++)
      #pragma unroll
      for (int j = 0; j < 4; j++)
        acc[i][j] += xa[i] * wb[j];
  }

  float avs[4], avd[4];
  {
    float4 s4 = *reinterpret_cast<const float4*>(a1s + q*64 + c0);
    float4 d4 = *reinterpret_cast<const float4*>(a1d + q*64 + c0);
    avs[0]=s4.x; avs[1]=s4.y; avs[2]=s4.z; avs[3]=s4.w;
    avd[0]=d4.x; avd[1]=d4.y; avd[2]=d4.z; avd[3]=d4.w;
  }
  #pragma unroll
  for (int i = 0; i < 4; i++){
    int nd = base + n0 + i;
    float sp = acc[i][0]*avs[0] + acc[i][1]*avs[1] + acc[i][2]*avs[2] + acc[i][3]*avs[3];
    float dp = acc[i][0]*avd[0] + acc[i][1]*avd[1] + acc[i][2]*avd[2] + acc[i][3]*avd[3];
    sPart[qg][n0+i] = sp;
    dPart[qg][n0+i] = dp;
    if (nd < nN){
      float4 o4 = make_float4(acc[i][0], acc[i][1], acc[i][2], acc[i][3]);
      *reinterpret_cast<float4*>(h1 + (size_t)nd*256 + q*64 + c0) = o4;
    }
  }
  __syncthreads();
  if (t < 64){
    int nd = base + t;
    if (nd < nN){
      float s = 0.f, d = 0.f;
      #pragma unroll
      for (int g = 0; g < 16; g++){ s += sPart[g][t]; d += dPart[g][t]; }
      as1[nd*4 + q] = s;
      ad1[nd*4 + q] = d;
    }
  }
}

// ---------------- lin2 as tiled GEMM: h2 = g1 @ W2; fused alpha2 ----------------
// grid ceil(N/64). K=256 in 4 chunks of 64. 4x4 reg tile/thread.
__global__ __launch_bounds__(256) void k_lin2t(const float* __restrict__ g1,
    const float* __restrict__ W2, const float* __restrict__ a2s, const float* __restrict__ a2d,
    float* __restrict__ h2, float* __restrict__ as2, float* __restrict__ ad2, int nN){
  int tile = blockIdx.x;
  int base = tile*64;
  __shared__ float xsT[64][68];
  __shared__ float ws [64][68];
  __shared__ float sPart[16][64];
  __shared__ float dPart[16][64];

  int t = threadIdx.x;
  int row = t >> 2, fq = t & 3;
  int ndl = base + row; if (ndl >= nN) ndl = nN - 1;
  const float* gr = g1 + (size_t)ndl*256;
  int n0 = (t & 15)*4, c0 = (t >> 4)*4, qg = t >> 4;
  float acc[4][4] = {};

  for (int k0 = 0; k0 < 256; k0 += 64){
    __syncthreads();
    #pragma unroll
    for (int j = 0; j < 4; j++){     // g1 chunk -> xsT (transposed)
      int f4 = j*4 + fq;
      float4 v = *reinterpret_cast<const float4*>(gr + k0 + f4*4);
      xsT[f4*4+0][row] = v.x; xsT[f4*4+1][row] = v.y;
      xsT[f4*4+2][row] = v.z; xsT[f4*4+3][row] = v.w;
    }
    #pragma unroll
    for (int j = 0; j < 4; j++){     // W2 chunk -> ws
      int f4 = j*4 + fq;
      float4 v = *reinterpret_cast<const float4*>(W2 + (size_t)(k0 + row)*64 + f4*4);
      *reinterpret_cast<float4*>(&ws[row][f4*4]) = v;
    }
    __syncthreads();
    #pragma unroll 8
    for (int k = 0; k < 64; k++){
      float4 xv = *reinterpret_cast<const float4*>(&xsT[k][n0]);
      float4 wv = *reinterpret_cast<const float4*>(&ws[k][c0]);
      float xa[4] = {xv.x, xv.y, xv.z, xv.w};
      float wb[4] = {wv.x, wv.y, wv.z, wv.w};
      #pragma unroll
      for (int i = 0; i < 4; i++)
        #pragma unroll
        for (int j = 0; j < 4; j++)
          acc[i][j] += xa[i] * wb[j];
    }
  }

  float avs[4], avd[4];
  {
    float4 s4 = *reinterpret_cast<const float4*>(a2s + c0);
    float4 d4 = *reinterpret_cast<const float4*>(a2d + c0);
    avs[0]=s4.x; avs[1]=s4.y; avs[2]=s4.z; avs[3]=s4.w;
    avd[0]=d4.x; avd[1]=d4.y; avd[2]=d4.z; avd[3]=d4.w;
  }
  #pragma unroll
  for (int i = 0; i < 4; i++){
    int nd = base + n0 + i;
    float sp = acc[i][0]*avs[0] + acc[i][1]*avs[1] + acc[i][2]*avs[2] + acc[i][3]*avs[3];
    float dp = acc[i][0]*avd[0] + acc[i][1]*avd[1] + acc[i][2]*avd[2] + acc[i][3]*avd[3];
    sPart[qg][n0+i] = sp;
    dPart[qg][n0+i] = dp;
    if (nd < nN){
      float4 o4 = make_float4(acc[i][0], acc[i][1], acc[i][2], acc[i][3]);
      *reinterpret_cast<float4*>(h2 + (size_t)nd*64 + c0) = o4;
    }
  }
  __syncthreads();
  if (t < 64){
    int nd = base + t;
    if (nd < nN){
      float s = 0.f, d = 0.f;
      #pragma unroll
      for (int g = 0; g < 16; g++){ s += sPart[g][t]; d += dPart[g][t]; }
      as2[nd] = s;
      ad2[nd] = d;
    }
  }
}

// ---------------- conv1 aggregate: edge-parallel alpha + vectorized gather ----------------
__global__ __launch_bounds__(64) void k_gat1(const int* __restrict__ off, const int* __restrict__ srcs,
    const float* __restrict__ as1, const float* __restrict__ ad1,
    const float* __restrict__ h1, const float* __restrict__ b1,
    float* __restrict__ g1, int nN){
  int n = blockIdx.x;
  int L = threadIdx.x;
  int hL = L >> 4, c4 = (L & 15)*4;
  __shared__ int   s_src[64];
  __shared__ float s_p[64][4];
  float ad[4];
  { float4 a = *reinterpret_cast<const float4*>(ad1 + (size_t)n*4);
    ad[0]=a.x; ad[1]=a.y; ad[2]=a.z; ad[3]=a.w; }
  int s0 = off[n], s1 = off[n+1];
  float m[4] = {-1e30f,-1e30f,-1e30f,-1e30f};
  float den[4] = {0.f,0.f,0.f,0.f};
  float4 acc = make_float4(0.f,0.f,0.f,0.f);
  for (int base = s0; base < s1; base += 64){
    int e = base + L;
    int cl = min(64, s1 - base);
    bool valid = (e < s1);
    int sv = 0; float v[4];
    if (valid){
      sv = srcs[e];
      float4 a = *reinterpret_cast<const float4*>(as1 + (size_t)sv*4);
      float av[4] = {a.x,a.y,a.z,a.w};
      #pragma unroll
      for (int h = 0; h < 4; h++){ float tt = av[h] + ad[h]; v[h] = (tt>0.f)?tt:0.2f*tt; }
    } else {
      #pragma unroll
      for (int h = 0; h < 4; h++) v[h] = -1e30f;
    }
    float sc[4];
    #pragma unroll
    for (int h = 0; h < 4; h++){
      float cm = wred_max(v[h]);
      float mn = fmaxf(m[h], cm);
      sc[h] = __expf(m[h] - mn);
      m[h] = mn;
      float p = valid ? __expf(v[h] - mn) : 0.f;
      den[h] = den[h]*sc[h] + wred_sum(p);
      if (valid) s_p[L][h] = p;
    }
    { float s4 = sc[hL]; acc.x*=s4; acc.y*=s4; acc.z*=s4; acc.w*=s4; }
    if (valid) s_src[L] = sv;
    __syncthreads();
    #pragma unroll 4
    for (int e2 = 0; e2 < cl; e2++){
      int sr = s_src[e2];
      float pp = s_p[e2][hL];
      float4 hv = *reinterpret_cast<const float4*>(h1 + (size_t)sr*256 + hL*64 + c4);
      acc.x += pp*hv.x; acc.y += pp*hv.y; acc.z += pp*hv.z; acc.w += pp*hv.w;
    }
    __syncthreads();
  }
  float dl = den[hL] + 1e-16f;
  float4 bb = *reinterpret_cast<const float4*>(b1 + hL*64 + c4);
  float o[4] = {acc.x/dl+bb.x, acc.y/dl+bb.y, acc.z/dl+bb.z, acc.w/dl+bb.w};
  #pragma unroll
  for (int j = 0; j < 4; j++) o[j] = (o[j] > 0.f) ? o[j] : expm1f(o[j]);   // ELU
  *reinterpret_cast<float4*>(g1 + (size_t)n*256 + hL*64 + c4) = make_float4(o[0],o[1],o[2],o[3]);
}

// ---------------- conv2 aggregate + b2 -> per-node vector g2[n][64] (NO atomics) ----------------
// shfl-broadcast with WAVE-UNIFORM trip count + clamped source lane (R5/R6 exec-mask bug fix).
__global__ __launch_bounds__(256) void k_gat2v(const int* __restrict__ off, const int* __restrict__ srcs,
    const float* __restrict__ as2, const float* __restrict__ ad2,
    const float* __restrict__ h2, const float* __restrict__ b2,
    float* __restrict__ g2, int nN){
  int w = threadIdx.x >> 6, L = threadIdx.x & 63;
  int n = blockIdx.x*4 + w;
  if (n >= nN) return;
  int g = L >> 4, c4 = (L & 15)*4;
  float ad = ad2[n];
  int s0 = off[n], s1 = off[n+1];
  float m = -1e30f, den = 0.f;
  float4 acc = make_float4(0.f,0.f,0.f,0.f);
  for (int base = s0; base < s1; base += 64){
    int e = base + L;
    int cl = min(64, s1 - base);
    bool valid = (e < s1);
    int sv = 0; float v = -1e30f;
    if (valid){
      sv = srcs[e];
      float tt = as2[sv] + ad;
      v = (tt>0.f)?tt:0.2f*tt;
    }
    float cm = wred_max(v);
    float mn = fmaxf(m, cm);
    float sc = __expf(m - mn);
    m = mn;
    float p = valid ? __expf(v - mn) : 0.f;
    den = den*sc + wred_sum(p);
    acc.x*=sc; acc.y*=sc; acc.z*=sc; acc.w*=sc;
    int iters = (cl + 3) >> 2;          // wave-uniform trip count
    for (int it = 0; it < iters; ++it){
      int e2   = it*4 + g;
      int esrc = (e2 < cl) ? e2 : (cl - 1);   // clamp -> source lane always active
      int   sr = __shfl(sv, esrc, 64);
      float pp = __shfl(p,  esrc, 64);
      if (e2 < cl){
        float4 hv = *reinterpret_cast<const float4*>(h2 + (size_t)sr*64 + c4);
        acc.x += pp*hv.x; acc.y += pp*hv.y; acc.z += pp*hv.z; acc.w += pp*hv.w;
      }
    }
  }
  #pragma unroll
  for (int s = 16; s <= 32; s <<= 1){
    acc.x += __shfl_xor(acc.x, s, 64);
    acc.y += __shfl_xor(acc.y, s, 64);
    acc.z += __shfl_xor(acc.z, s, 64);
    acc.w += __shfl_xor(acc.w, s, 64);
  }
  float dl = den + 1e-16f;
  if (L < 16){
    float4 b4 = *reinterpret_cast<const float4*>(b2 + c4);
    float4 o4 = make_float4(acc.x/dl + b4.x, acc.y/dl + b4.y,
                            acc.z/dl + b4.z, acc.w/dl + b4.w);
    *reinterpret_cast<float4*>(g2 + (size_t)n*64 + c4) = o4;
  }
}

// ---------------- bucket starts from SORTED batch (boundary detect, no atomics) ----------------
__global__ void k_bstart(const int* __restrict__ batch, int nN, int B, int* __restrict__ bstart){
  int i = blockIdx.x*blockDim.x + threadIdx.x;
  if (i < nN){
    int prev = (i == 0) ? -1 : batch[i-1];
    int cur  = batch[i];
    for (int b = prev+1; b <= cur; b++) bstart[b] = i;
  } else if (i == nN){
    int last = batch[nN-1];
    for (int b = last+1; b <= B; b++) bstart[b] = nN;
  }
}

// ---------------- pool: out[b] = mean(g2 rows) @ Wl + bl ----------------
__global__ __launch_bounds__(64) void k_pool(const float* __restrict__ g2, const int* __restrict__ bstart,
    const float* __restrict__ Wl, const float* __restrict__ bl, float* __restrict__ out, int B){
  int b = blockIdx.x, c = threadIdx.x;
  int r0 = bstart[b], r1 = bstart[b+1];
  float s = 0.f;
  int i = r0;
  for (; i + 4 <= r1; i += 4){
    s += g2[(size_t)(i+0)*64 + c];
    s += g2[(size_t)(i+1)*64 + c];
    s += g2[(size_t)(i+2)*64 + c];
    s += g2[(size_t)(i+3)*64 + c];
  }
  for (; i < r1; i++) s += g2[(size_t)i*64 + c];
  float g = s / fmaxf((float)(r1 - r0), 1.f);
  float v = wred_sum(g * Wl[c]);
  if (c == 0) out[b] = v + bl[0];
}

extern "C" void kernel_launch(void* const* d_in, const int* in_sizes, int n_in,
                              void* d_out, int out_size, void* d_ws, size_t ws_size,
                              hipStream_t stream){
  const float* x    = (const float*)d_in[0];
  const int*   ntyp = (const int*)  d_in[1];
  const int*   ei   = (const int*)  d_in[2];
  const int*   batch= (const int*)  d_in[3];
  const float* Wt = (const float*)d_in[4];
  const float* bt = (const float*)d_in[5];
  const float* Wv = (const float*)d_in[6];
  const float* bv = (const float*)d_in[7];
  const float* Wa = (const float*)d_in[8];
  const float* ba = (const float*)d_in[9];
  const float* W1 = (const float*)d_in[10];
  const float* a1s= (const float*)d_in[11];
  const float* a1d= (const float*)d_in[12];
  const float* b1 = (const float*)d_in[13];
  const float* W2 = (const float*)d_in[14];
  const float* a2s= (const float*)d_in[15];
  const float* a2d= (const float*)d_in[16];
  const float* b2 = (const float*)d_in[17];
  const float* Wl = (const float*)d_in[18];
  const float* bl = (const float*)d_in[19];

  const int N = in_sizes[1];
  const int E = in_sizes[2] / 2;
  const int B = out_size;
  const int nblk = (N + 255)/256;

  char* ws = (char*)d_ws;
  size_t o = 0;
  auto alloc = [&](size_t bytes) -> void* {
    void* p = ws + o;
    o = (o + bytes + 255) & ~(size_t)255;
    return p;
  };
  int*   csr_off = (int*)  alloc((size_t)(N+1)*4);
  int*   pos     = (int*)  alloc((size_t)N*4);
  int*   csr_src = (int*)  alloc((size_t)(E+N)*4);
  float* as1     = (float*)alloc((size_t)N*4*4);
  float* ad1     = (float*)alloc((size_t)N*4*4);
  float* h0      = (float*)alloc((size_t)N*64*4);
  float* h1      = (float*)alloc((size_t)N*256*4);
  float* g1      = (float*)alloc((size_t)N*256*4);
  int*   bstart  = (int*)  alloc((size_t)(B+1)*4);
  int*   bcnt    = (int*)  alloc((size_t)nblk*3*4);
  int*   boff    = (int*)  alloc((size_t)nblk*3*4);
  int*   toff    = (int*)  alloc(3*4);
  int*   tcnt    = (int*)  alloc(3*4);
  int*   order   = (int*)  alloc((size_t)N*4);
  // aliases (dead-after relationships): h2 reuses h0; alpha2 reuses alpha1; g2 reuses h1
  float* h2  = h0;        // h0 dead after k_lin1t
  float* as2 = as1;       // as1/ad1 dead after k_gat1
  float* ad2 = ad1;
  float* g2  = h1;        // h1 dead after k_gat1

  // type buckets (ballot-based, no global atomics)
  k_bcount  <<<nblk, 256, 0, stream>>>(ntyp, N, nblk, bcnt);
  k_bscan   <<<1, 1024, 0, stream>>>(bcnt, nblk, N, boff, toff, tcnt);
  k_bscatter<<<nblk, 256, 0, stream>>>(ntyp, N, nblk, boff, order);

  // CSR build
  k_deg_init <<<(N + 255)/256, 256, 0, stream>>>(pos, N);
  k_deg_edges<<<(E + 255)/256, 256, 0, stream>>>(ei, E, pos);
  k_scan     <<<1, 1024, 0, stream>>>(pos, csr_off, N);
  k_pos_copy <<<(N + 255)/256, 256, 0, stream>>>(csr_off, pos, N);
  k_scatter  <<<(E + N + 255)/256, 256, 0, stream>>>(ei, E, N, pos, csr_src);

  // batch bucket starts (sorted batch; no atomics)
  k_bstart<<<(N + 1 + 255)/256, 256, 0, stream>>>(batch, N, B, bstart);

  // projection (bucketed tiled GEMM)
  {
    dim3 g((N + 63)/64, 3);
    k_projgemm<<<g, 256, 0, stream>>>(x, order, toff, tcnt, Wt, bt, Wv, bv, Wa, ba, h0);
  }

  // lin1 as tiled GEMM (4 head-quadrants)
  {
    dim3 g((N + 63)/64, 4);
    k_lin1t<<<g, 256, 0, stream>>>(h0, W1, a1s, a1d, h1, as1, ad1, N);
  }
  k_gat1<<<N, 64, 0, stream>>>(csr_off, csr_src, as1, ad1, h1, b1, g1, N);
  k_lin2t<<<(N + 63)/64, 256, 0, stream>>>(g1, W2, a2s, a2d, h2, as2, ad2, N);
  k_gat2v<<<(N + 3)/4, 256, 0, stream>>>(csr_off, csr_src, as2, ad2, h2, b2, g2, N);
  k_pool<<<B, 64, 0, stream>>>(g2, bstart, Wl, bl, (float*)d_out, B);
}

// Round 9
// 386.587 us; speedup vs baseline: 3.7227x; 1.1876x over previous
//
#include <hip/hip_runtime.h>
#include <cstdint>
#include <cstddef>

#define TEXTD 768
#define VISD  512
#define AUDD  128

__device__ __forceinline__ float wred_sum(float v){
  #pragma unroll
  for (int m = 32; m >= 1; m >>= 1) v += __shfl_xor(v, m, 64);
  return v;
}
__device__ __forceinline__ float wred_max(float v){
  #pragma unroll
  for (int m = 32; m >= 1; m >>= 1) v = fmaxf(v, __shfl_xor(v, m, 64));
  return v;
}

// ---------------- type bucketing (hierarchical ballot sort; NO global atomics) ----------------
__global__ __launch_bounds__(256) void k_bcount(const int* __restrict__ ntype, int nN, int nblk,
                                                int* __restrict__ bcnt){
  int b = blockIdx.x;
  int i = b*256 + threadIdx.x;
  int lane = threadIdx.x & 63, w = threadIdx.x >> 6;
  int ty = (i < nN) ? ntype[i] : -1;
  __shared__ int wc[4][3];
  #pragma unroll
  for (int t = 0; t < 3; t++){
    unsigned long long m = __ballot(ty == t);
    if (lane == 0) wc[w][t] = __popcll(m);
  }
  __syncthreads();
  if (threadIdx.x < 3){
    int t = threadIdx.x;
    bcnt[t*nblk + b] = wc[0][t] + wc[1][t] + wc[2][t] + wc[3][t];
  }
}
__global__ __launch_bounds__(1024) void k_bscan(const int* __restrict__ bcnt, int nblk, int nN,
                                                int* __restrict__ boff, int* __restrict__ toff,
                                                int* __restrict__ tcnt){
  __shared__ int s[2048];          // supports nblk*3 <= 2048
  int n3 = nblk*3;
  int t = threadIdx.x;
  for (int i = t; i < n3; i += 1024) s[i] = bcnt[i];
  __syncthreads();
  if (t == 0){
    int run = 0;
    for (int i = 0; i < n3; i++){ int v = s[i]; s[i] = run; run += v; }
  }
  __syncthreads();
  for (int i = t; i < n3; i += 1024) boff[i] = s[i];
  if (t == 0){
    toff[0] = 0;         toff[1] = s[nblk];           toff[2] = s[2*nblk];
    tcnt[0] = s[nblk];   tcnt[1] = s[2*nblk]-s[nblk]; tcnt[2] = nN - s[2*nblk];
  }
}
__global__ __launch_bounds__(256) void k_bscatter(const int* __restrict__ ntype, int nN, int nblk,
                                                  const int* __restrict__ boff, int* __restrict__ order){
  int b = blockIdx.x;
  int i = b*256 + threadIdx.x;
  int lane = threadIdx.x & 63, w = threadIdx.x >> 6;
  int ty = (i < nN) ? ntype[i] : -1;
  __shared__ int wc[4][3];
  __shared__ int woff[4][3];
  unsigned long long masks[3];
  #pragma unroll
  for (int t = 0; t < 3; t++){
    masks[t] = __ballot(ty == t);
    if (lane == 0) wc[w][t] = __popcll(masks[t]);
  }
  __syncthreads();
  if (threadIdx.x < 3){
    int t = threadIdx.x, run = 0;
    #pragma unroll
    for (int ww = 0; ww < 4; ww++){ woff[ww][t] = run; run += wc[ww][t]; }
  }
  __syncthreads();
  if (ty >= 0){
    int r = __popcll(masks[ty] & ((1ULL << lane) - 1ULL));
    int pos = boff[ty*nblk + b] + woff[w][ty] + r;
    order[pos] = i;
  }
}

// ---------------- projection as bucketed tiled GEMM ----------------
__global__ __launch_bounds__(256) void k_projgemm(const float* __restrict__ x,
    const int* __restrict__ order, const int* __restrict__ toff, const int* __restrict__ tcnt,
    const float* __restrict__ Wt, const float* __restrict__ bt,
    const float* __restrict__ Wv, const float* __restrict__ bv,
    const float* __restrict__ Wa, const float* __restrict__ ba,
    float* __restrict__ h0){
  int ty = blockIdx.y;
  int cnt = tcnt[ty];
  int tile = blockIdx.x;
  if (tile*64 >= cnt) return;
  const float* W; const float* bias; int dim;
  if (ty == 0)      { W = Wt; bias = bt; dim = TEXTD; }
  else if (ty == 1) { W = Wv; bias = bv; dim = VISD; }
  else              { W = Wa; bias = ba; dim = AUDD; }
  int off = toff[ty];

  __shared__ float xsT[64][68];
  __shared__ float ws [64][68];
  __shared__ int   nid[64];

  int t = threadIdx.x;
  if (t < 64){
    int idx = tile*64 + t;
    nid[t] = (idx < cnt) ? order[off + idx] : -1;
  }
  __syncthreads();

  int node_l = t & 63;
  int ndl = nid[node_l];
  const float* xrow = x + (size_t)(ndl < 0 ? 0 : ndl) * TEXTD;
  int wrow = t >> 2, wu = t & 3;
  int wvq  = t >> 6;
  int n0 = (t & 15)*4, c0 = (t >> 4)*4;
  float acc[4][4] = {};

  for (int k0 = 0; k0 < dim; k0 += 64){
    __syncthreads();
    #pragma unroll
    for (int j = 0; j < 4; j++){
      int f4 = wvq*4 + j;
      float4 v = *reinterpret_cast<const float4*>(xrow + k0 + f4*4);
      xsT[f4*4+0][node_l] = v.x;
      xsT[f4*4+1][node_l] = v.y;
      xsT[f4*4+2][node_l] = v.z;
      xsT[f4*4+3][node_l] = v.w;
    }
    #pragma unroll
    for (int j = 0; j < 4; j++){
      int f4 = j*4 + wu;
      float4 v = *reinterpret_cast<const float4*>(W + (size_t)(k0 + wrow)*64 + f4*4);
      *reinterpret_cast<float4*>(&ws[wrow][f4*4]) = v;
    }
    __syncthreads();
    #pragma unroll 8
    for (int kk = 0; kk < 64; kk++){
      float4 xv = *reinterpret_cast<const float4*>(&xsT[kk][n0]);
      float4 wv = *reinterpret_cast<const float4*>(&ws[kk][c0]);
      float xa[4] = {xv.x, xv.y, xv.z, xv.w};
      float wb[4] = {wv.x, wv.y, wv.z, wv.w};
      #pragma unroll
      for (int i = 0; i < 4; i++)
        #pragma unroll
        for (int j = 0; j < 4; j++)
          acc[i][j] += xa[i] * wb[j];
    }
  }

  float4 b4 = *reinterpret_cast<const float4*>(bias + c0);
  float bb[4] = {b4.x, b4.y, b4.z, b4.w};
  #pragma unroll
  for (int i = 0; i < 4; i++){
    int nd = nid[n0 + i];
    if (nd >= 0){
      float4 o4 = make_float4(acc[i][0]+bb[0], acc[i][1]+bb[1], acc[i][2]+bb[2], acc[i][3]+bb[3]);
      *reinterpret_cast<float4*>(h0 + (size_t)nd*64 + c0) = o4;
    }
  }
}

// ---------------- CSR build ----------------
__global__ void k_deg_init(int* __restrict__ deg, int nN){
  int i = blockIdx.x*blockDim.x + threadIdx.x;
  if (i < nN) deg[i] = 1;                    // self-loop
}
__global__ void k_deg_edges(const int* __restrict__ ei, int E, int* __restrict__ deg){
  int i = blockIdx.x*blockDim.x + threadIdx.x;
  if (i < E) atomicAdd(&deg[ei[E + i]], 1);  // dst row
}
__global__ __launch_bounds__(1024) void k_scan(const int* __restrict__ deg, int* __restrict__ off, int n){
  __shared__ int wsum[16];
  __shared__ int carry_s;
  int t = threadIdx.x, lane = t & 63, w = t >> 6;
  if (t == 0) carry_s = 0;
  __syncthreads();
  for (int base = 0; base < n; base += 1024){
    int i = base + t;
    int v = (i < n) ? deg[i] : 0;
    int orig = v;
    #pragma unroll
    for (int o = 1; o < 64; o <<= 1){ int u = __shfl_up(v, o, 64); if (lane >= o) v += u; }
    if (lane == 63) wsum[w] = v;
    __syncthreads();
    if (t < 16){
      int xv = wsum[t];
      #pragma unroll
      for (int o = 1; o < 16; o <<= 1){ int u = __shfl_up(xv, o, 16); if (t >= o) xv += u; }
      wsum[t] = xv;
    }
    __syncthreads();
    int wbase = (w == 0) ? 0 : wsum[w-1];
    int incl = v + wbase;
    int carry = carry_s;
    if (i < n) off[i] = carry + incl - orig;
    __syncthreads();
    if (t == 0) carry_s = carry + wsum[15];
    __syncthreads();
  }
  if (threadIdx.x == 0) off[n] = carry_s;
}
__global__ void k_pos_copy(const int* __restrict__ off, int* __restrict__ pos, int nN){
  int i = blockIdx.x*blockDim.x + threadIdx.x;
  if (i < nN) pos[i] = off[i];
}
__global__ void k_scatter(const int* __restrict__ ei, int E, int nN,
                          int* __restrict__ pos, int* __restrict__ csr_src){
  int i = blockIdx.x*blockDim.x + threadIdx.x;
  int total = E + nN;
  if (i >= total) return;
  int s, d;
  if (i < E){ s = ei[i]; d = ei[E + i]; } else { s = i - E; d = s; }
  int p = atomicAdd(&pos[d], 1);
  csr_src[p] = s;
}

// ---------------- alpha1 precompute: wfs[k][h] = W1[k, h-block] . a1s[h] (one block) ------------
__global__ __launch_bounds__(256) void k_afold(const float* __restrict__ W1,
    const float* __restrict__ a1s, const float* __restrict__ a1d,
    float* __restrict__ wfs, float* __restrict__ wfd){
  int t = threadIdx.x;           // 256 = 64 k x 4 h
  int k = t & 63, h = t >> 6;
  const float* wr = W1 + (size_t)k*256 + h*64;
  const float* as = a1s + h*64;
  const float* ad = a1d + h*64;
  float s = 0.f, d = 0.f;
  for (int c = 0; c < 64; c += 4){
    float4 w  = *reinterpret_cast<const float4*>(wr + c);
    float4 sa = *reinterpret_cast<const float4*>(as + c);
    float4 da = *reinterpret_cast<const float4*>(ad + c);
    s += w.x*sa.x + w.y*sa.y + w.z*sa.z + w.w*sa.w;
    d += w.x*da.x + w.y*da.y + w.z*da.z + w.w*da.w;
  }
  wfs[k*4 + h] = s;
  wfd[k*4 + h] = d;
}

// ---------------- alpha1: as1/ad1 = h0 @ wfs/wfd  (h1 never materialized) ----------------
__global__ __launch_bounds__(256) void k_alpha1(const float* __restrict__ h0,
    const float* __restrict__ wfs, const float* __restrict__ wfd,
    float* __restrict__ as1, float* __restrict__ ad1, int nN){
  __shared__ float xsT[64][68];   // [k][node]
  __shared__ float sW[64][8];     // [k][h:4 s | 4 d]
  int t = threadIdx.x;
  int base = blockIdx.x*64;
  int row = t >> 2, fq = t & 3;
  {
    int nd = base + row; if (nd >= nN) nd = nN - 1;
    const float* hr = h0 + (size_t)nd*64;
    #pragma unroll
    for (int j = 0; j < 4; j++){
      int f4 = j*4 + fq;
      float4 v = *reinterpret_cast<const float4*>(hr + f4*4);
      xsT[f4*4+0][row] = v.x; xsT[f4*4+1][row] = v.y;
      xsT[f4*4+2][row] = v.z; xsT[f4*4+3][row] = v.w;
    }
  }
  if (t < 64){
    float4 s4 = *reinterpret_cast<const float4*>(wfs + t*4);
    float4 d4 = *reinterpret_cast<const float4*>(wfd + t*4);
    sW[t][0]=s4.x; sW[t][1]=s4.y; sW[t][2]=s4.z; sW[t][3]=s4.w;
    sW[t][4]=d4.x; sW[t][5]=d4.y; sW[t][6]=d4.z; sW[t][7]=d4.w;
  }
  __syncthreads();
  int node = t >> 2, h = t & 3;
  float s = 0.f, d = 0.f;
  #pragma unroll 8
  for (int k = 0; k < 64; k++){
    float xv = xsT[k][node];
    s += xv * sW[k][h];
    d += xv * sW[k][h+4];
  }
  int nd = base + node;
  if (nd < nN){ as1[nd*4 + h] = s; ad1[nd*4 + h] = d; }
}

// ---------------- conv1 aggregate over h0 (256B rows!): z[n][h*64+k] = (sum p_h * h0[src][k])/den_h
__global__ __launch_bounds__(64) void k_gat1z(const int* __restrict__ off, const int* __restrict__ srcs,
    const float* __restrict__ as1, const float* __restrict__ ad1,
    const float* __restrict__ h0, float* __restrict__ z, int nN){
  int n = blockIdx.x;
  int L = threadIdx.x;
  int hL = L >> 4, c4 = (L & 15)*4;
  __shared__ int   s_src[64];
  __shared__ float s_p[64][4];
  float ad[4];
  { float4 a = *reinterpret_cast<const float4*>(ad1 + (size_t)n*4);
    ad[0]=a.x; ad[1]=a.y; ad[2]=a.z; ad[3]=a.w; }
  int s0 = off[n], s1 = off[n+1];
  float m[4] = {-1e30f,-1e30f,-1e30f,-1e30f};
  float den[4] = {0.f,0.f,0.f,0.f};
  float4 acc = make_float4(0.f,0.f,0.f,0.f);
  for (int base = s0; base < s1; base += 64){
    int e = base + L;
    int cl = min(64, s1 - base);
    bool valid = (e < s1);
    int sv = 0; float v[4];
    if (valid){
      sv = srcs[e];
      float4 a = *reinterpret_cast<const float4*>(as1 + (size_t)sv*4);
      float av[4] = {a.x,a.y,a.z,a.w};
      #pragma unroll
      for (int h = 0; h < 4; h++){ float tt = av[h] + ad[h]; v[h] = (tt>0.f)?tt:0.2f*tt; }
    } else {
      #pragma unroll
      for (int h = 0; h < 4; h++) v[h] = -1e30f;
    }
    float sc[4];
    #pragma unroll
    for (int h = 0; h < 4; h++){
      float cm = wred_max(v[h]);
      float mn = fmaxf(m[h], cm);
      sc[h] = __expf(m[h] - mn);
      m[h] = mn;
      float p = valid ? __expf(v[h] - mn) : 0.f;
      den[h] = den[h]*sc[h] + wred_sum(p);
      if (valid) s_p[L][h] = p;
    }
    { float s4 = sc[hL]; acc.x*=s4; acc.y*=s4; acc.z*=s4; acc.w*=s4; }
    if (valid) s_src[L] = sv;
    __syncthreads();
    #pragma unroll 4
    for (int e2 = 0; e2 < cl; e2++){
      int sr = s_src[e2];
      float pp = s_p[e2][hL];
      float4 hv = *reinterpret_cast<const float4*>(h0 + (size_t)sr*64 + c4);
      acc.x += pp*hv.x; acc.y += pp*hv.y; acc.z += pp*hv.z; acc.w += pp*hv.w;
    }
    __syncthreads();
  }
  float dl = den[hL] + 1e-16f;
  *reinterpret_cast<float4*>(z + (size_t)n*256 + hL*64 + c4) =
      make_float4(acc.x/dl, acc.y/dl, acc.z/dl, acc.w/dl);
}

// ---------------- g1 = ELU(z_h @ W1_h + b1): 4 batched 64x64 GEMMs ----------------
__global__ __launch_bounds__(256) void k_glin1(const float* __restrict__ z,
    const float* __restrict__ W1, const float* __restrict__ b1,
    float* __restrict__ g1, int nN){
  int tile = blockIdx.x, q = blockIdx.y;
  int base = tile*64;
  __shared__ float xsT[64][68];     // [k][node] from z columns q*64..+63
  __shared__ float ws [64][68];     // [k][chan] W1 quadrant q
  int t = threadIdx.x;
  int row = t >> 2, fq = t & 3;
  {
    int nd = base + row; if (nd >= nN) nd = nN - 1;
    const float* zr = z + (size_t)nd*256 + q*64;
    #pragma unroll
    for (int j = 0; j < 4; j++){
      int f4 = j*4 + fq;
      float4 v = *reinterpret_cast<const float4*>(zr + f4*4);
      xsT[f4*4+0][row] = v.x; xsT[f4*4+1][row] = v.y;
      xsT[f4*4+2][row] = v.z; xsT[f4*4+3][row] = v.w;
    }
  }
  #pragma unroll
  for (int j = 0; j < 4; j++){
    int f4 = j*4 + fq;
    float4 v = *reinterpret_cast<const float4*>(W1 + (size_t)row*256 + q*64 + f4*4);
    *reinterpret_cast<float4*>(&ws[row][f4*4]) = v;
  }
  __syncthreads();

  int n0 = (t & 15)*4, c0 = (t >> 4)*4;
  float acc[4][4] = {};
  #pragma unroll 8
  for (int k = 0; k < 64; k++){
    float4 xv = *reinterpret_cast<const float4*>(&xsT[k][n0]);
    float4 wv = *reinterpret_cast<const float4*>(&ws[k][c0]);
    float xa[4] = {xv.x, xv.y, xv.z, xv.w};
    float wb[4] = {wv.x, wv.y, wv.z, wv.w};
    #pragma unroll
    for (int i = 0; i < 4; i++)
      #pragma unroll
      for (int j = 0; j < 4; j++)
        acc[i][j] += xa[i] * wb[j];
  }
  float4 b4 = *reinterpret_cast<const float4*>(b1 + q*64 + c0);
  float bb[4] = {b4.x, b4.y, b4.z, b4.w};
  #pragma unroll
  for (int i = 0; i < 4; i++){
    int nd = base + n0 + i;
    if (nd < nN){
      float o[4];
      #pragma unroll
      for (int j = 0; j < 4; j++){
        float u = acc[i][j] + bb[j];
        o[j] = (u > 0.f) ? u : expm1f(u);      // ELU
      }
      *reinterpret_cast<float4*>(g1 + (size_t)nd*256 + q*64 + c0) =
          make_float4(o[0], o[1], o[2], o[3]);
    }
  }
}

// ---------------- lin2 as tiled GEMM: h2 = g1 @ W2; fused alpha2 ----------------
__global__ __launch_bounds__(256) void k_lin2t(const float* __restrict__ g1,
    const float* __restrict__ W2, const float* __restrict__ a2s, const float* __restrict__ a2d,
    float* __restrict__ h2, float* __restrict__ as2, float* __restrict__ ad2, int nN){
  int tile = blockIdx.x;
  int base = tile*64;
  __shared__ float xsT[64][68];
  __shared__ float ws [64][68];
  __shared__ float sPart[16][64];
  __shared__ float dPart[16][64];

  int t = threadIdx.x;
  int row = t >> 2, fq = t & 3;
  int ndl = base + row; if (ndl >= nN) ndl = nN - 1;
  const float* gr = g1 + (size_t)ndl*256;
  int n0 = (t & 15)*4, c0 = (t >> 4)*4, qg = t >> 4;
  float acc[4][4] = {};

  for (int k0 = 0; k0 < 256; k0 += 64){
    __syncthreads();
    #pragma unroll
    for (int j = 0; j < 4; j++){
      int f4 = j*4 + fq;
      float4 v = *reinterpret_cast<const float4*>(gr + k0 + f4*4);
      xsT[f4*4+0][row] = v.x; xsT[f4*4+1][row] = v.y;
      xsT[f4*4+2][row] = v.z; xsT[f4*4+3][row] = v.w;
    }
    #pragma unroll
    for (int j = 0; j < 4; j++){
      int f4 = j*4 + fq;
      float4 v = *reinterpret_cast<const float4*>(W2 + (size_t)(k0 + row)*64 + f4*4);
      *reinterpret_cast<float4*>(&ws[row][f4*4]) = v;
    }
    __syncthreads();
    #pragma unroll 8
    for (int k = 0; k < 64; k++){
      float4 xv = *reinterpret_cast<const float4*>(&xsT[k][n0]);
      float4 wv = *reinterpret_cast<const float4*>(&ws[k][c0]);
      float xa[4] = {xv.x, xv.y, xv.z, xv.w};
      float wb[4] = {wv.x, wv.y, wv.z, wv.w};
      #pragma unroll
      for (int i = 0; i < 4; i++)
        #pragma unroll
        for (int j = 0; j < 4; j++)
          acc[i][j] += xa[i] * wb[j];
    }
  }

  float avs[4], avd[4];
  {
    float4 s4 = *reinterpret_cast<const float4*>(a2s + c0);
    float4 d4 = *reinterpret_cast<const float4*>(a2d + c0);
    avs[0]=s4.x; avs[1]=s4.y; avs[2]=s4.z; avs[3]=s4.w;
    avd[0]=d4.x; avd[1]=d4.y; avd[2]=d4.z; avd[3]=d4.w;
  }
  #pragma unroll
  for (int i = 0; i < 4; i++){
    int nd = base + n0 + i;
    float sp = acc[i][0]*avs[0] + acc[i][1]*avs[1] + acc[i][2]*avs[2] + acc[i][3]*avs[3];
    float dp = acc[i][0]*avd[0] + acc[i][1]*avd[1] + acc[i][2]*avd[2] + acc[i][3]*avd[3];
    sPart[qg][n0+i] = sp;
    dPart[qg][n0+i] = dp;
    if (nd < nN){
      float4 o4 = make_float4(acc[i][0], acc[i][1], acc[i][2], acc[i][3]);
      *reinterpret_cast<float4*>(h2 + (size_t)nd*64 + c0) = o4;
    }
  }
  __syncthreads();
  if (t < 64){
    int nd = base + t;
    if (nd < nN){
      float s = 0.f, d = 0.f;
      #pragma unroll
      for (int g = 0; g < 16; g++){ s += sPart[g][t]; d += dPart[g][t]; }
      as2[nd] = s;
      ad2[nd] = d;
    }
  }
}

// ---------------- conv2 aggregate + b2 -> per-node vector g2[n][64] (NO atomics) ----------------
// shfl-broadcast with WAVE-UNIFORM trip count + clamped source lane (R5/R6 exec-mask bug fix).
__global__ __launch_bounds__(256) void k_gat2v(const int* __restrict__ off, const int* __restrict__ srcs,
    const float* __restrict__ as2, const float* __restrict__ ad2,
    const float* __restrict__ h2, const float* __restrict__ b2,
    float* __restrict__ g2, int nN){
  int w = threadIdx.x >> 6, L = threadIdx.x & 63;
  int n = blockIdx.x*4 + w;
  if (n >= nN) return;
  int g = L >> 4, c4 = (L & 15)*4;
  float ad = ad2[n];
  int s0 = off[n], s1 = off[n+1];
  float m = -1e30f, den = 0.f;
  float4 acc = make_float4(0.f,0.f,0.f,0.f);
  for (int base = s0; base < s1; base += 64){
    int e = base + L;
    int cl = min(64, s1 - base);
    bool valid = (e < s1);
    int sv = 0; float v = -1e30f;
    if (valid){
      sv = srcs[e];
      float tt = as2[sv] + ad;
      v = (tt>0.f)?tt:0.2f*tt;
    }
    float cm = wred_max(v);
    float mn = fmaxf(m, cm);
    float sc = __expf(m - mn);
    m = mn;
    float p = valid ? __expf(v - mn) : 0.f;
    den = den*sc + wred_sum(p);
    acc.x*=sc; acc.y*=sc; acc.z*=sc; acc.w*=sc;
    int iters = (cl + 3) >> 2;          // wave-uniform trip count
    for (int it = 0; it < iters; ++it){
      int e2   = it*4 + g;
      int esrc = (e2 < cl) ? e2 : (cl - 1);   // clamp -> source lane always active
      int   sr = __shfl(sv, esrc, 64);
      float pp = __shfl(p,  esrc, 64);
      if (e2 < cl){
        float4 hv = *reinterpret_cast<const float4*>(h2 + (size_t)sr*64 + c4);
        acc.x += pp*hv.x; acc.y += pp*hv.y; acc.z += pp*hv.z; acc.w += pp*hv.w;
      }
    }
  }
  #pragma unroll
  for (int s = 16; s <= 32; s <<= 1){
    acc.x += __shfl_xor(acc.x, s, 64);
    acc.y += __shfl_xor(acc.y, s, 64);
    acc.z += __shfl_xor(acc.z, s, 64);
    acc.w += __shfl_xor(acc.w, s, 64);
  }
  float dl = den + 1e-16f;
  if (L < 16){
    float4 b4 = *reinterpret_cast<const float4*>(b2 + c4);
    float4 o4 = make_float4(acc.x/dl + b4.x, acc.y/dl + b4.y,
                            acc.z/dl + b4.z, acc.w/dl + b4.w);
    *reinterpret_cast<float4*>(g2 + (size_t)n*64 + c4) = o4;
  }
}

// ---------------- bucket starts from SORTED batch (boundary detect, no atomics) ----------------
__global__ void k_bstart(const int* __restrict__ batch, int nN, int B, int* __restrict__ bstart){
  int i = blockIdx.x*blockDim.x + threadIdx.x;
  if (i < nN){
    int prev = (i == 0) ? -1 : batch[i-1];
    int cur  = batch[i];
    for (int b = prev+1; b <= cur; b++) bstart[b] = i;
  } else if (i == nN){
    int last = batch[nN-1];
    for (int b = last+1; b <= B; b++) bstart[b] = nN;
  }
}

// ---------------- pool: out[b] = mean(g2 rows) @ Wl + bl ----------------
__global__ __launch_bounds__(64) void k_pool(const float* __restrict__ g2, const int* __restrict__ bstart,
    const float* __restrict__ Wl, const float* __restrict__ bl, float* __restrict__ out, int B){
  int b = blockIdx.x, c = threadIdx.x;
  int r0 = bstart[b], r1 = bstart[b+1];
  float s = 0.f;
  int i = r0;
  for (; i + 4 <= r1; i += 4){
    s += g2[(size_t)(i+0)*64 + c];
    s += g2[(size_t)(i+1)*64 + c];
    s += g2[(size_t)(i+2)*64 + c];
    s += g2[(size_t)(i+3)*64 + c];
  }
  for (; i < r1; i++) s += g2[(size_t)i*64 + c];
  float g = s / fmaxf((float)(r1 - r0), 1.f);
  float v = wred_sum(g * Wl[c]);
  if (c == 0) out[b] = v + bl[0];
}

extern "C" void kernel_launch(void* const* d_in, const int* in_sizes, int n_in,
                              void* d_out, int out_size, void* d_ws, size_t ws_size,
                              hipStream_t stream){
  const float* x    = (const float*)d_in[0];
  const int*   ntyp = (const int*)  d_in[1];
  const int*   ei   = (const int*)  d_in[2];
  const int*   batch= (const int*)  d_in[3];
  const float* Wt = (const float*)d_in[4];
  const float* bt = (const float*)d_in[5];
  const float* Wv = (const float*)d_in[6];
  const float* bv = (const float*)d_in[7];
  const float* Wa = (const float*)d_in[8];
  const float* ba = (const float*)d_in[9];
  const float* W1 = (const float*)d_in[10];
  const float* a1s= (const float*)d_in[11];
  const float* a1d= (const float*)d_in[12];
  const float* b1 = (const float*)d_in[13];
  const float* W2 = (const float*)d_in[14];
  const float* a2s= (const float*)d_in[15];
  const float* a2d= (const float*)d_in[16];
  const float* b2 = (const float*)d_in[17];
  const float* Wl = (const float*)d_in[18];
  const float* bl = (const float*)d_in[19];

  const int N = in_sizes[1];
  const int E = in_sizes[2] / 2;
  const int B = out_size;
  const int nblk = (N + 255)/256;

  char* ws = (char*)d_ws;
  size_t o = 0;
  auto alloc = [&](size_t bytes) -> void* {
    void* p = ws + o;
    o = (o + bytes + 255) & ~(size_t)255;
    return p;
  };
  int*   csr_off = (int*)  alloc((size_t)(N+1)*4);
  int*   pos     = (int*)  alloc((size_t)N*4);
  int*   csr_src = (int*)  alloc((size_t)(E+N)*4);
  float* as1     = (float*)alloc((size_t)N*4*4);
  float* ad1     = (float*)alloc((size_t)N*4*4);
  float* h0      = (float*)alloc((size_t)N*64*4);
  float* zbuf    = (float*)alloc((size_t)N*256*4);
  float* g1      = (float*)alloc((size_t)N*256*4);
  int*   bstart  = (int*)  alloc((size_t)(B+1)*4);
  int*   bcnt    = (int*)  alloc((size_t)nblk*3*4);
  int*   boff    = (int*)  alloc((size_t)nblk*3*4);
  int*   toff    = (int*)  alloc(3*4);
  int*   tcnt    = (int*)  alloc(3*4);
  int*   order   = (int*)  alloc((size_t)N*4);
  float* wfs     = (float*)alloc(256*4);
  float* wfd     = (float*)alloc(256*4);
  // aliases: h2 reuses h0 (h0 dead after k_gat1z); alpha2 reuses alpha1 (dead after k_gat1z);
  //          g2 reuses zbuf (dead after k_glin1)
  float* h2  = h0;
  float* as2 = as1;
  float* ad2 = ad1;
  float* g2  = zbuf;

  // type buckets (ballot-based, no global atomics)
  k_bcount  <<<nblk, 256, 0, stream>>>(ntyp, N, nblk, bcnt);
  k_bscan   <<<1, 1024, 0, stream>>>(bcnt, nblk, N, boff, toff, tcnt);
  k_bscatter<<<nblk, 256, 0, stream>>>(ntyp, N, nblk, boff, order);

  // CSR build
  k_deg_init <<<(N + 255)/256, 256, 0, stream>>>(pos, N);
  k_deg_edges<<<(E + 255)/256, 256, 0, stream>>>(ei, E, pos);
  k_scan     <<<1, 1024, 0, stream>>>(pos, csr_off, N);
  k_pos_copy <<<(N + 255)/256, 256, 0, stream>>>(csr_off, pos, N);
  k_scatter  <<<(E + N + 255)/256, 256, 0, stream>>>(ei, E, N, pos, csr_src);

  // batch bucket starts (sorted batch; no atomics)
  k_bstart<<<(N + 1 + 255)/256, 256, 0, stream>>>(batch, N, B, bstart);

  // alpha1 folded weights (independent of h0; can run early)
  k_afold<<<1, 256, 0, stream>>>(W1, a1s, a1d, wfs, wfd);

  // projection (bucketed tiled GEMM)
  {
    dim3 g((N + 63)/64, 3);
    k_projgemm<<<g, 256, 0, stream>>>(x, order, toff, tcnt, Wt, bt, Wv, bv, Wa, ba, h0);
  }

  // conv1: alphas -> aggregate h0 -> per-head GEMM (+b1, ELU)
  k_alpha1<<<(N + 63)/64, 256, 0, stream>>>(h0, wfs, wfd, as1, ad1, N);
  k_gat1z <<<N, 64, 0, stream>>>(csr_off, csr_src, as1, ad1, h0, zbuf, N);
  {
    dim3 g((N + 63)/64, 4);
    k_glin1<<<g, 256, 0, stream>>>(zbuf, W1, b1, g1, N);
  }

  // conv2 + pooling
  k_lin2t<<<(N + 63)/64, 256, 0, stream>>>(g1, W2, a2s, a2d, h2, as2, ad2, N);
  k_gat2v<<<(N + 3)/4, 256, 0, stream>>>(csr_off, csr_src, as2, ad2, h2, b2, g2, N);
  k_pool<<<B, 64, 0, stream>>>(g2, bstart, Wl, bl, (float*)d_out, B);
}